// Round 1
// baseline (6046.989 us; speedup 1.0000x reference)
//
#include <hip/hip_runtime.h>
#include <math.h>

#define BB 4
#define LL 1024
#define DIN 64
#define DD 512
#define HH 8
#define DH 64
#define NLAYER 3
#define DFF 2048
#define FEAT 530   // D + 2 + 2*8

__device__ __forceinline__ float gelu_exact(float x) {
    return 0.5f * x * (1.0f + erff(x * 0.7071067811865475f));
}

__device__ __forceinline__ float wave_reduce_sum(float v) {
    #pragma unroll
    for (int o = 32; o; o >>= 1) v += __shfl_down(v, o);
    return v;
}
__device__ __forceinline__ float wave_reduce_max(float v) {
    #pragma unroll
    for (int o = 32; o; o >>= 1) v = fmaxf(v, __shfl_down(v, o));
    return v;
}

// ---------------- delay feature encoder: e[B,D] ----------------
__global__ __launch_bounds__(512) void delay_kernel(
    const float* __restrict__ delay, const float* __restrict__ w1, const float* __restrict__ b1,
    const float* __restrict__ w2, const float* __restrict__ b2,
    const float* __restrict__ lng, const float* __restrict__ lnb,
    float* __restrict__ e)
{
    int b = blockIdx.x;
    int t = threadIdx.x;
    __shared__ float g1[DD];
    __shared__ float red[16];
    float t1 = delay[b] * w1[t] + b1[t];
    g1[t] = gelu_exact(t1);
    __syncthreads();
    const float* wr = w2 + (size_t)t * DD;
    float s = b2[t];
    for (int j = 0; j < DD; j += 4) {
        float4 w4 = *(const float4*)(wr + j);
        s += w4.x * g1[j] + w4.y * g1[j+1] + w4.z * g1[j+2] + w4.w * g1[j+3];
    }
    float rs = wave_reduce_sum(s);
    float rss = wave_reduce_sum(s * s);
    int lane = t & 63, w = t >> 6;
    if (lane == 0) { red[w] = rs; red[8 + w] = rss; }
    __syncthreads();
    float mean = 0.f, msq = 0.f;
    #pragma unroll
    for (int i = 0; i < 8; ++i) { mean += red[i]; msq += red[8 + i]; }
    mean *= (1.0f / DD); msq *= (1.0f / DD);
    float rstd = rsqrtf(msq - mean * mean + 1e-5f);
    e[(size_t)b * DD + t] = (s - mean) * rstd * lng[t] + lnb[t];
}

// ------ fused: input proj + corr positional encoding + delay-add -> h ------
__global__ __launch_bounds__(256) void embed_kernel(
    const float* __restrict__ x, const float* __restrict__ c_local, const float* __restrict__ c_sink,
    const int* __restrict__ lengths,
    const float* __restrict__ in_w, const float* __restrict__ in_b,
    const float* __restrict__ cpe_w, const float* __restrict__ cpe_b,
    const float* __restrict__ cpe_g, const float* __restrict__ cpe_lb,
    const float* __restrict__ gain_p, const float* __restrict__ e,
    float* __restrict__ h)
{
    int row = blockIdx.x;
    int b = row >> 10, l = row & 1023;
    int t = threadIdx.x;
    __shared__ float z[FEAT];
    __shared__ float xs[DIN];
    __shared__ float red[16];

    // sinusoidal PE portion of z
    for (int d = t; d < DD; d += 256) {
        int i = d >> 1;
        float dv = expf((float)(2 * i) * (-0.017988946135618352f)); // -ln(1e4)/512
        float ang = (float)l * dv;
        z[d] = (d & 1) ? cosf(ang) : sinf(ang);
    }
    float cl = c_local[(size_t)b * LL + l]; cl = fminf(fmaxf(cl, 0.f), 1.f);
    float cs = c_sink [(size_t)b * LL + l]; cs = fminf(fmaxf(cs, 0.f), 1.f);
    if (t == 0) { z[512] = cl; z[513] = cs; }
    if (t < 8)  { float c = (float)t * (1.0f / 7.0f); float df = (cl - c) / 0.200001f; z[514 + t] = expf(-0.5f * df * df); }
    if (t >= 8 && t < 16) { int j = t - 8; float c = (float)j * (1.0f / 7.0f); float df = (cs - c) / 0.200001f; z[522 + j] = expf(-0.5f * df * df); }
    if (t < 16) ((float4*)xs)[t] = ((const float4*)(x + (size_t)row * DIN))[t];
    __syncthreads();

    float cacc[2], hacc[2];
    #pragma unroll
    for (int u = 0; u < 2; ++u) {
        int d = t + u * 256;
        const float* wr = cpe_w + (size_t)d * FEAT;
        float a = cpe_b[d];
        for (int j = 0; j < FEAT; j += 2) {       // rows only 8B-aligned (530 floats)
            float2 w2v = *(const float2*)(wr + j);
            a += w2v.x * z[j] + w2v.y * z[j + 1];
        }
        cacc[u] = a;
        const float* ir = in_w + (size_t)d * DIN;
        float hb = in_b[d];
        #pragma unroll
        for (int j = 0; j < DIN; j += 4) {
            float4 w4 = *(const float4*)(ir + j);
            hb += w4.x * xs[j] + w4.y * xs[j+1] + w4.z * xs[j+2] + w4.w * xs[j+3];
        }
        hacc[u] = hb;
    }
    // LN over the 512 cpe pre-activations
    float s = cacc[0] + cacc[1];
    float ss = cacc[0] * cacc[0] + cacc[1] * cacc[1];
    float rs = wave_reduce_sum(s), rss = wave_reduce_sum(ss);
    int lane = t & 63, w = t >> 6;
    if (lane == 0) { red[w] = rs; red[8 + w] = rss; }
    __syncthreads();
    float mean = 0.f, msq = 0.f;
    #pragma unroll
    for (int i = 0; i < 4; ++i) { mean += red[i]; msq += red[8 + i]; }
    mean *= (1.0f / DD); msq *= (1.0f / DD);
    float rstd = rsqrtf(msq - mean * mean + 1e-5f);
    bool maskp = (l >= lengths[b]);
    float gain = *gain_p;
    #pragma unroll
    for (int u = 0; u < 2; ++u) {
        int d = t + u * 256;
        float pe = maskp ? 0.f : gain * ((cacc[u] - mean) * rstd * cpe_g[d] + cpe_lb[d]);
        h[(size_t)row * DD + d] = hacc[u] + e[(size_t)b * DD + d] + pe;
    }
}

// ---------------- row LayerNorm (D=512), one block per row ----------------
__global__ __launch_bounds__(256) void ln_kernel(
    const float* __restrict__ in, float* __restrict__ out,
    const float* __restrict__ g, const float* __restrict__ bta)
{
    int row = blockIdx.x; int t = threadIdx.x;
    __shared__ float red[16];
    const float* xr = in + (size_t)row * DD;
    float2 v = ((const float2*)xr)[t];
    float s = v.x + v.y, ss = v.x * v.x + v.y * v.y;
    float rs = wave_reduce_sum(s), rss = wave_reduce_sum(ss);
    int lane = t & 63, w = t >> 6;
    if (lane == 0) { red[w] = rs; red[8 + w] = rss; }
    __syncthreads();
    float mean = 0.f, msq = 0.f;
    #pragma unroll
    for (int i = 0; i < 4; ++i) { mean += red[i]; msq += red[8 + i]; }
    mean *= (1.0f / DD); msq *= (1.0f / DD);
    float rstd = rsqrtf(msq - mean * mean + 1e-5f);
    float2 gg = ((const float2*)g)[t], bb = ((const float2*)bta)[t];
    float2 o;
    o.x = (v.x - mean) * rstd * gg.x + bb.x;
    o.y = (v.y - mean) * rstd * gg.y + bb.y;
    ((float2*)(out + (size_t)row * DD))[t] = o;
}

// ---- tiled f32 GEMM: out[M,N] = act(A[M,K] @ W[N,K]^T + bias) (+resid) ----
__global__ __launch_bounds__(256) void gemm_kernel(
    const float* __restrict__ A, const float* __restrict__ W,
    const float* __restrict__ bias, const float* __restrict__ resid,
    float* __restrict__ out, int M, int N, int K, int act)
{
    __shared__ float As[64][17];
    __shared__ float Ws[64][17];
    int bm = blockIdx.y * 64, bn = blockIdx.x * 64;
    int t = threadIdx.x;
    int tx = t & 15, ty = t >> 4;
    float acc[4][4] = {};
    for (int k0 = 0; k0 < K; k0 += 16) {
        #pragma unroll
        for (int j = 0; j < 4; ++j) {
            int idx = t + 256 * j;
            int m = idx >> 4, kk = idx & 15;
            As[m][kk] = A[(size_t)(bm + m) * K + k0 + kk];
            Ws[m][kk] = W[(size_t)(bn + m) * K + k0 + kk];
        }
        __syncthreads();
        #pragma unroll
        for (int kk = 0; kk < 16; ++kk) {
            float a[4], bv[4];
            #pragma unroll
            for (int i = 0; i < 4; ++i) a[i] = As[ty * 4 + i][kk];
            #pragma unroll
            for (int j = 0; j < 4; ++j) bv[j] = Ws[tx * 4 + j][kk];
            #pragma unroll
            for (int i = 0; i < 4; ++i)
                #pragma unroll
                for (int j = 0; j < 4; ++j)
                    acc[i][j] = fmaf(a[i], bv[j], acc[i][j]);
        }
        __syncthreads();
    }
    #pragma unroll
    for (int i = 0; i < 4; ++i) {
        #pragma unroll
        for (int j = 0; j < 4; ++j) {
            int m = bm + ty * 4 + i, n = bn + tx * 4 + j;
            float v = acc[i][j] + bias[n];
            if (act) v = gelu_exact(v);
            if (resid) v += resid[(size_t)m * N + n];
            out[(size_t)m * N + n] = v;
        }
    }
}

// ------------- fused attention: one block per (b, h, q) -------------
__global__ __launch_bounds__(256) void attn_kernel(
    const float* __restrict__ qkv,
    const float* __restrict__ c_local, const float* __restrict__ c_sink,
    const int* __restrict__ lengths,
    const float* __restrict__ alpha_p, const float* __restrict__ beta_p,
    const float* __restrict__ floor_p, const float* __restrict__ gamma_p,
    float* __restrict__ o)
{
    int bid = blockIdx.x;
    int q = bid & 1023;
    int hh = (bid >> 10) & 7;
    int b = bid >> 13;
    int t = threadIdx.x;
    __shared__ float qs[DH];
    __shared__ float sc[LL];
    __shared__ float red[8];
    __shared__ float part[4][DH];
    int len = lengths[b];
    const float alpha = *alpha_p, beta = *beta_p, flr = *floor_p, gmm = *gamma_p;
    if (t < 16) ((float4*)qs)[t] = ((const float4*)(qkv + (size_t)(b * LL + q) * 1536 + hh * DH))[t];
    __syncthreads();
    bool maskq = (q >= len);
    float sv[4];
    #pragma unroll
    for (int c = 0; c < 4; ++c) {
        int k = t + 256 * c;
        const float* kp = qkv + (size_t)(b * LL + k) * 1536 + 512 + hh * DH;
        float s = 0.f;
        #pragma unroll
        for (int d = 0; d < DH; d += 4) {
            float4 kv = *(const float4*)(kp + d);
            s += kv.x * qs[d] + kv.y * qs[d+1] + kv.z * qs[d+2] + kv.w * qs[d+3];
        }
        s *= 0.125f;  // 1/sqrt(64)
        bool maskk = (k >= len);
        if (!maskq && !maskk) {
            if (k == q - 1) {
                // c_edge overwrite semantics: q==1 or q==L-1 keep c_local[q], else c_local[q-1]
                float cval = (q == 1 || q == LL - 1) ? c_local[(size_t)b * LL + q]
                                                     : c_local[(size_t)b * LL + q - 1];
                s += alpha * cval;
            } else if (k == q + 1) {
                s += alpha * c_local[(size_t)b * LL + q + 1];
            }
        }
        if (q == 0 && !maskk) {
            float csv = c_sink[(size_t)b * LL + k];
            csv = fminf(fmaxf(csv, 0.f), 1.f);
            s += beta * (flr + (1.f - flr) * powf(csv + 1e-6f, gmm));
        }
        if (maskk) s -= 10000.0f;
        sv[c] = s;
    }
    // row max
    float lm = fmaxf(fmaxf(sv[0], sv[1]), fmaxf(sv[2], sv[3]));
    lm = wave_reduce_max(lm);
    int lane = t & 63, w = t >> 6;
    if (lane == 0) red[w] = lm;
    __syncthreads();
    float m = fmaxf(fmaxf(red[0], red[1]), fmaxf(red[2], red[3]));
    __syncthreads();
    // p = exp(clamp(s-m, -20, 20)), denom
    float ps = 0.f;
    #pragma unroll
    for (int c = 0; c < 4; ++c) {
        float p = expf(fminf(fmaxf(sv[c] - m, -20.f), 20.f));
        sc[t + 256 * c] = p;
        ps += p;
    }
    float rs = wave_reduce_sum(ps);
    if (lane == 0) red[w] = rs;
    __syncthreads();
    float denom = red[0] + red[1] + red[2] + red[3];
    // phase 2: o[d] = sum_k p[k] * V[k,d]
    int d = t & 63, grp = t >> 6;
    const float* vb = qkv + (size_t)b * LL * 1536 + 1024 + hh * DH + d;
    float a = 0.f;
    for (int k = grp * 256; k < grp * 256 + 256; ++k)
        a += sc[k] * vb[(size_t)k * 1536];
    part[grp][d] = a;
    __syncthreads();
    if (t < DH) {
        float val = (part[0][t] + part[1][t] + part[2][t] + part[3][t]) / denom;
        o[(size_t)(b * LL + q) * DD + hh * DH + t] = val;
    }
}

extern "C" void kernel_launch(void* const* d_in, const int* in_sizes, int n_in,
                              void* d_out, int out_size, void* d_ws, size_t ws_size,
                              hipStream_t stream)
{
    const float* x          = (const float*)d_in[0];
    const int*   lengths    = (const int*)  d_in[1];
    const float* input_delay= (const float*)d_in[2];
    const float* c_local    = (const float*)d_in[3];
    const float* c_sink     = (const float*)d_in[4];
    const float* in_w       = (const float*)d_in[5];
    const float* in_b       = (const float*)d_in[6];
    const float* de_w1      = (const float*)d_in[7];
    const float* de_b1      = (const float*)d_in[8];
    const float* de_w2      = (const float*)d_in[9];
    const float* de_b2      = (const float*)d_in[10];
    const float* de_ln_g    = (const float*)d_in[11];
    const float* de_ln_b    = (const float*)d_in[12];
    const float* cpe_w      = (const float*)d_in[13];
    const float* cpe_b      = (const float*)d_in[14];
    const float* cpe_ln_g   = (const float*)d_in[15];
    const float* cpe_ln_b   = (const float*)d_in[16];
    const float* gain       = (const float*)d_in[17];
    const float* alpha      = (const float*)d_in[18];
    const float* beta       = (const float*)d_in[19];
    const float* floorp     = (const float*)d_in[20];
    const float* gammap     = (const float*)d_in[21];
    const float* inproj_w   = (const float*)d_in[22];
    const float* inproj_b   = (const float*)d_in[23];
    const float* outproj_w  = (const float*)d_in[24];
    const float* outproj_b  = (const float*)d_in[25];
    const float* ln1_g      = (const float*)d_in[26];
    const float* ln1_b      = (const float*)d_in[27];
    const float* ln2_g      = (const float*)d_in[28];
    const float* ln2_b      = (const float*)d_in[29];
    const float* ff_w1      = (const float*)d_in[30];
    const float* ff_b1      = (const float*)d_in[31];
    const float* ff_w2      = (const float*)d_in[32];
    const float* ff_b2      = (const float*)d_in[33];
    const float* out_ln_g   = (const float*)d_in[34];
    const float* out_ln_b   = (const float*)d_in[35];

    const int M = BB * LL;  // 4096
    float* ws  = (float*)d_ws;
    float* h   = ws;                         // M*DD
    float* hn  = h + (size_t)M * DD;         // M*DD  (also reused as attn output)
    float* big = hn + (size_t)M * DD;        // M*DFF (shared by qkv [M*1536] and ff [M*2048])
    float* e   = big + (size_t)M * DFF;      // BB*DD
    float* qkvb = big;
    float* ffb  = big;
    float* ob   = hn;                        // attn out overwrites LN1 output (dead by then)

    delay_kernel<<<BB, 512, 0, stream>>>(input_delay, de_w1, de_b1, de_w2, de_b2, de_ln_g, de_ln_b, e);
    embed_kernel<<<M, 256, 0, stream>>>(x, c_local, c_sink, lengths, in_w, in_b,
                                        cpe_w, cpe_b, cpe_ln_g, cpe_ln_b, gain, e, h);

    for (int i = 0; i < NLAYER; ++i) {
        ln_kernel<<<M, 256, 0, stream>>>(h, hn, ln1_g + (size_t)i * DD, ln1_b + (size_t)i * DD);
        gemm_kernel<<<dim3((3 * DD) / 64, M / 64), 256, 0, stream>>>(
            hn, inproj_w + (size_t)i * 3 * DD * DD, inproj_b + (size_t)i * 3 * DD,
            nullptr, qkvb, M, 3 * DD, DD, 0);
        attn_kernel<<<BB * HH * LL, 256, 0, stream>>>(qkvb, c_local, c_sink, lengths,
                                                      alpha, beta, floorp, gammap, ob);
        gemm_kernel<<<dim3(DD / 64, M / 64), 256, 0, stream>>>(
            ob, outproj_w + (size_t)i * DD * DD, outproj_b + (size_t)i * DD,
            h, h, M, DD, DD, 0);
        ln_kernel<<<M, 256, 0, stream>>>(h, hn, ln2_g + (size_t)i * DD, ln2_b + (size_t)i * DD);
        gemm_kernel<<<dim3(DFF / 64, M / 64), 256, 0, stream>>>(
            hn, ff_w1 + (size_t)i * DFF * DD, ff_b1 + (size_t)i * DFF,
            nullptr, ffb, M, DFF, DD, 1);
        gemm_kernel<<<dim3(DD / 64, M / 64), 256, 0, stream>>>(
            ffb, ff_w2 + (size_t)i * DD * DFF, ff_b2 + (size_t)i * DD,
            h, h, M, DD, DFF, 0);
    }
    ln_kernel<<<M, 256, 0, stream>>>(h, (float*)d_out, out_ln_g, out_ln_b);
}

// Round 2
// 3638.287 us; speedup vs baseline: 1.6620x; 1.6620x over previous
//
#include <hip/hip_runtime.h>
#include <math.h>

#define BB 4
#define LL 1024
#define DIN 64
#define DD 512
#define HH 8
#define DH 64
#define NLAYER 3
#define DFF 2048
#define FEAT 530   // D + 2 + 2*8
#define BQ 64
#define BKT 64

__device__ __forceinline__ float gelu_exact(float x) {
    return 0.5f * x * (1.0f + erff(x * 0.7071067811865475f));
}

__device__ __forceinline__ float wave_reduce_sum(float v) {
    #pragma unroll
    for (int o = 32; o; o >>= 1) v += __shfl_down(v, o);
    return v;
}

// ---------------- delay feature encoder: e[B,D] ----------------
__global__ __launch_bounds__(512) void delay_kernel(
    const float* __restrict__ delay, const float* __restrict__ w1, const float* __restrict__ b1,
    const float* __restrict__ w2, const float* __restrict__ b2,
    const float* __restrict__ lng, const float* __restrict__ lnb,
    float* __restrict__ e)
{
    int b = blockIdx.x;
    int t = threadIdx.x;
    __shared__ float g1[DD];
    __shared__ float red[16];
    float t1 = delay[b] * w1[t] + b1[t];
    g1[t] = gelu_exact(t1);
    __syncthreads();
    const float* wr = w2 + (size_t)t * DD;
    float s = b2[t];
    for (int j = 0; j < DD; j += 4) {
        float4 w4 = *(const float4*)(wr + j);
        s += w4.x * g1[j] + w4.y * g1[j+1] + w4.z * g1[j+2] + w4.w * g1[j+3];
    }
    float rs = wave_reduce_sum(s);
    float rss = wave_reduce_sum(s * s);
    int lane = t & 63, w = t >> 6;
    if (lane == 0) { red[w] = rs; red[8 + w] = rss; }
    __syncthreads();
    float mean = 0.f, msq = 0.f;
    #pragma unroll
    for (int i = 0; i < 8; ++i) { mean += red[i]; msq += red[8 + i]; }
    mean *= (1.0f / DD); msq *= (1.0f / DD);
    float rstd = rsqrtf(msq - mean * mean + 1e-5f);
    e[(size_t)b * DD + t] = (s - mean) * rstd * lng[t] + lnb[t];
}

// ------ fused: input proj + corr positional encoding + delay-add -> h ------
__global__ __launch_bounds__(256) void embed_kernel(
    const float* __restrict__ x, const float* __restrict__ c_local, const float* __restrict__ c_sink,
    const int* __restrict__ lengths,
    const float* __restrict__ in_w, const float* __restrict__ in_b,
    const float* __restrict__ cpe_w, const float* __restrict__ cpe_b,
    const float* __restrict__ cpe_g, const float* __restrict__ cpe_lb,
    const float* __restrict__ gain_p, const float* __restrict__ e,
    float* __restrict__ h)
{
    int row = blockIdx.x;
    int b = row >> 10, l = row & 1023;
    int t = threadIdx.x;
    __shared__ float z[FEAT];
    __shared__ float xs[DIN];
    __shared__ float red[16];

    for (int d = t; d < DD; d += 256) {
        int i = d >> 1;
        float dv = expf((float)(2 * i) * (-0.017988946135618352f)); // -ln(1e4)/512
        float ang = (float)l * dv;
        z[d] = (d & 1) ? cosf(ang) : sinf(ang);
    }
    float cl = c_local[(size_t)b * LL + l]; cl = fminf(fmaxf(cl, 0.f), 1.f);
    float cs = c_sink [(size_t)b * LL + l]; cs = fminf(fmaxf(cs, 0.f), 1.f);
    if (t == 0) { z[512] = cl; z[513] = cs; }
    if (t < 8)  { float c = (float)t * (1.0f / 7.0f); float df = (cl - c) / 0.200001f; z[514 + t] = expf(-0.5f * df * df); }
    if (t >= 8 && t < 16) { int j = t - 8; float c = (float)j * (1.0f / 7.0f); float df = (cs - c) / 0.200001f; z[522 + j] = expf(-0.5f * df * df); }
    if (t < 16) ((float4*)xs)[t] = ((const float4*)(x + (size_t)row * DIN))[t];
    __syncthreads();

    float cacc[2], hacc[2];
    #pragma unroll
    for (int u = 0; u < 2; ++u) {
        int d = t + u * 256;
        const float* wr = cpe_w + (size_t)d * FEAT;
        float a = cpe_b[d];
        for (int j = 0; j < FEAT; j += 2) {
            float2 w2v = *(const float2*)(wr + j);
            a += w2v.x * z[j] + w2v.y * z[j + 1];
        }
        cacc[u] = a;
        const float* ir = in_w + (size_t)d * DIN;
        float hb = in_b[d];
        #pragma unroll
        for (int j = 0; j < DIN; j += 4) {
            float4 w4 = *(const float4*)(ir + j);
            hb += w4.x * xs[j] + w4.y * xs[j+1] + w4.z * xs[j+2] + w4.w * xs[j+3];
        }
        hacc[u] = hb;
    }
    float s = cacc[0] + cacc[1];
    float ss = cacc[0] * cacc[0] + cacc[1] * cacc[1];
    float rs = wave_reduce_sum(s), rss = wave_reduce_sum(ss);
    int lane = t & 63, w = t >> 6;
    if (lane == 0) { red[w] = rs; red[8 + w] = rss; }
    __syncthreads();
    float mean = 0.f, msq = 0.f;
    #pragma unroll
    for (int i = 0; i < 4; ++i) { mean += red[i]; msq += red[8 + i]; }
    mean *= (1.0f / DD); msq *= (1.0f / DD);
    float rstd = rsqrtf(msq - mean * mean + 1e-5f);
    bool maskp = (l >= lengths[b]);
    float gain = *gain_p;
    #pragma unroll
    for (int u = 0; u < 2; ++u) {
        int d = t + u * 256;
        float pe = maskp ? 0.f : gain * ((cacc[u] - mean) * rstd * cpe_g[d] + cpe_lb[d]);
        h[(size_t)row * DD + d] = hacc[u] + e[(size_t)b * DD + d] + pe;
    }
}

// ---------------- row LayerNorm (D=512), one block per row ----------------
__global__ __launch_bounds__(256) void ln_kernel(
    const float* __restrict__ in, float* __restrict__ out,
    const float* __restrict__ g, const float* __restrict__ bta)
{
    int row = blockIdx.x; int t = threadIdx.x;
    __shared__ float red[16];
    const float* xr = in + (size_t)row * DD;
    float2 v = ((const float2*)xr)[t];
    float s = v.x + v.y, ss = v.x * v.x + v.y * v.y;
    float rs = wave_reduce_sum(s), rss = wave_reduce_sum(ss);
    int lane = t & 63, w = t >> 6;
    if (lane == 0) { red[w] = rs; red[8 + w] = rss; }
    __syncthreads();
    float mean = 0.f, msq = 0.f;
    #pragma unroll
    for (int i = 0; i < 4; ++i) { mean += red[i]; msq += red[8 + i]; }
    mean *= (1.0f / DD); msq *= (1.0f / DD);
    float rstd = rsqrtf(msq - mean * mean + 1e-5f);
    float2 gg = ((const float2*)g)[t], bb = ((const float2*)bta)[t];
    float2 o;
    o.x = (v.x - mean) * rstd * gg.x + bb.x;
    o.y = (v.y - mean) * rstd * gg.y + bb.y;
    ((float2*)(out + (size_t)row * DD))[t] = o;
}

// ---- tiled f32 GEMM: out[M,N] = act(A[M,K] @ W[N,K]^T + bias) (+resid) ----
__global__ __launch_bounds__(256) void gemm_kernel(
    const float* __restrict__ A, const float* __restrict__ W,
    const float* __restrict__ bias, const float* __restrict__ resid,
    float* __restrict__ out, int M, int N, int K, int act)
{
    __shared__ float As[64][17];
    __shared__ float Ws[64][17];
    int bm = blockIdx.y * 64, bn = blockIdx.x * 64;
    int t = threadIdx.x;
    int tx = t & 15, ty = t >> 4;
    float acc[4][4] = {};
    for (int k0 = 0; k0 < K; k0 += 16) {
        #pragma unroll
        for (int j = 0; j < 4; ++j) {
            int idx = t + 256 * j;
            int m = idx >> 4, kk = idx & 15;
            As[m][kk] = A[(size_t)(bm + m) * K + k0 + kk];
            Ws[m][kk] = W[(size_t)(bn + m) * K + k0 + kk];
        }
        __syncthreads();
        #pragma unroll
        for (int kk = 0; kk < 16; ++kk) {
            float a[4], bv[4];
            #pragma unroll
            for (int i = 0; i < 4; ++i) a[i] = As[ty * 4 + i][kk];
            #pragma unroll
            for (int j = 0; j < 4; ++j) bv[j] = Ws[tx * 4 + j][kk];
            #pragma unroll
            for (int i = 0; i < 4; ++i)
                #pragma unroll
                for (int j = 0; j < 4; ++j)
                    acc[i][j] = fmaf(a[i], bv[j], acc[i][j]);
        }
        __syncthreads();
    }
    #pragma unroll
    for (int i = 0; i < 4; ++i) {
        #pragma unroll
        for (int j = 0; j < 4; ++j) {
            int m = bm + ty * 4 + i, n = bn + tx * 4 + j;
            float v = acc[i][j] + bias[n];
            if (act) v = gelu_exact(v);
            if (resid) v += resid[(size_t)m * N + n];
            out[(size_t)m * N + n] = v;
        }
    }
}

// ------------- flash attention: one block per (b, h, 64-row Q tile) -------------
__global__ __launch_bounds__(256) void attn_flash(
    const float* __restrict__ qkv,
    const float* __restrict__ c_local, const float* __restrict__ c_sink,
    const int* __restrict__ lengths,
    const float* __restrict__ alpha_p, const float* __restrict__ beta_p,
    const float* __restrict__ floor_p, const float* __restrict__ gamma_p,
    float* __restrict__ o)
{
    __shared__ float Qs[BQ][DH + 4];
    __shared__ float KP[BKT][DH + 4];   // K tile (swizzled), reused for P (linear)
    __shared__ float Vs[BKT][DH + 4];   // V tile (swizzled)

    int q0 = blockIdx.x * BQ;
    int hh = blockIdx.y;
    int b  = blockIdx.z;
    int t  = threadIdx.x;
    int tx = t & 15, ty = t >> 4;
    int len = lengths[b];
    const float alpha = *alpha_p, beta = *beta_p, flr = *floor_p, gmm = *gamma_p;

    // load Q tile (linear layout)
    #pragma unroll
    for (int u = 0; u < 4; ++u) {
        int idx = t + 256 * u;
        int r = idx >> 4, c4 = idx & 15;
        *(float4*)&Qs[r][c4 * 4] =
            *(const float4*)(qkv + (size_t)(b * LL + q0 + r) * 1536 + hh * DH + c4 * 4);
    }

    float m_run[4], l_run[4], accO[4][4] = {};
    #pragma unroll
    for (int i = 0; i < 4; ++i) { m_run[i] = -1e30f; l_run[i] = 0.f; }

    for (int k0 = 0; k0 < LL; k0 += BKT) {
        // load K,V tiles with chunk-XOR swizzle: chunk' = c4 ^ ((r>>2)&7)
        #pragma unroll
        for (int u = 0; u < 4; ++u) {
            int idx = t + 256 * u;
            int r = idx >> 4, c4 = idx & 15;
            int sc4 = c4 ^ ((r >> 2) & 7);
            size_t rowb = (size_t)(b * LL + k0 + r) * 1536 + hh * DH + c4 * 4;
            *(float4*)&KP[r][sc4 * 4] = *(const float4*)(qkv + rowb + 512);
            *(float4*)&Vs[r][sc4 * 4] = *(const float4*)(qkv + rowb + 1024);
        }
        __syncthreads();

        // S = Q K^T (register 4x4 tile, float4 over d)
        float s[4][4] = {};
        #pragma unroll
        for (int d4 = 0; d4 < 16; ++d4) {
            float4 a4[4], b4[4];
            #pragma unroll
            for (int i = 0; i < 4; ++i) a4[i] = *(const float4*)&Qs[ty * 4 + i][d4 * 4];
            #pragma unroll
            for (int j = 0; j < 4; ++j) {
                int r = tx * 4 + j;
                b4[j] = *(const float4*)&KP[r][(d4 ^ ((r >> 2) & 7)) * 4];
            }
            #pragma unroll
            for (int i = 0; i < 4; ++i)
                #pragma unroll
                for (int j = 0; j < 4; ++j) {
                    s[i][j] = fmaf(a4[i].x, b4[j].x, s[i][j]);
                    s[i][j] = fmaf(a4[i].y, b4[j].y, s[i][j]);
                    s[i][j] = fmaf(a4[i].z, b4[j].z, s[i][j]);
                    s[i][j] = fmaf(a4[i].w, b4[j].w, s[i][j]);
                }
        }
        __syncthreads();   // everyone done reading K before P overwrites

        // bias + mask + online softmax; write P into KP (linear layout)
        #pragma unroll
        for (int i = 0; i < 4; ++i) {
            int qi = q0 + ty * 4 + i;
            bool maskq = (qi >= len);
            float tm = -1e30f;
            #pragma unroll
            for (int j = 0; j < 4; ++j) {
                int kj = k0 + tx * 4 + j;
                float v = s[i][j] * 0.125f;
                bool maskk = (kj >= len);
                if (!maskq && !maskk) {
                    if (kj == qi - 1) {
                        float cval = (qi == 1 || qi == LL - 1) ? c_local[(size_t)b * LL + qi]
                                                               : c_local[(size_t)b * LL + qi - 1];
                        v += alpha * cval;
                    } else if (kj == qi + 1) {
                        v += alpha * c_local[(size_t)b * LL + qi + 1];
                    }
                }
                if (qi == 0 && !maskk) {
                    float csv = c_sink[(size_t)b * LL + kj];
                    csv = fminf(fmaxf(csv, 0.f), 1.f);
                    v += beta * (flr + (1.f - flr) * powf(csv + 1e-6f, gmm));
                }
                if (maskk) v -= 10000.f;
                s[i][j] = v;
                tm = fmaxf(tm, v);
            }
            #pragma unroll
            for (int msk = 1; msk < 16; msk <<= 1) tm = fmaxf(tm, __shfl_xor(tm, msk));
            float mnew = fmaxf(m_run[i], tm);
            float scl = __expf(m_run[i] - mnew);
            float rowsum = 0.f;
            #pragma unroll
            for (int j = 0; j < 4; ++j) {
                float p = __expf(s[i][j] - mnew);
                s[i][j] = p;
                rowsum += p;
            }
            #pragma unroll
            for (int msk = 1; msk < 16; msk <<= 1) rowsum += __shfl_xor(rowsum, msk);
            l_run[i] = l_run[i] * scl + rowsum;
            m_run[i] = mnew;
            #pragma unroll
            for (int j = 0; j < 4; ++j) {
                accO[i][j] *= scl;
                KP[ty * 4 + i][tx * 4 + j] = s[i][j];
            }
        }
        __syncthreads();

        // O += P @ V  (P linear in KP, V swizzled)
        #pragma unroll
        for (int k4 = 0; k4 < 16; ++k4) {
            float4 a4[4];
            #pragma unroll
            for (int i = 0; i < 4; ++i) a4[i] = *(const float4*)&KP[ty * 4 + i][k4 * 4];
            #pragma unroll
            for (int kk = 0; kk < 4; ++kk) {
                float4 b4 = *(const float4*)&Vs[k4 * 4 + kk][(tx ^ (k4 & 7)) * 4];
                float av[4] = { a4[0].x, a4[1].x, a4[2].x, a4[3].x };
                if (kk == 1) { av[0] = a4[0].y; av[1] = a4[1].y; av[2] = a4[2].y; av[3] = a4[3].y; }
                if (kk == 2) { av[0] = a4[0].z; av[1] = a4[1].z; av[2] = a4[2].z; av[3] = a4[3].z; }
                if (kk == 3) { av[0] = a4[0].w; av[1] = a4[1].w; av[2] = a4[2].w; av[3] = a4[3].w; }
                #pragma unroll
                for (int i = 0; i < 4; ++i) {
                    accO[i][0] = fmaf(av[i], b4.x, accO[i][0]);
                    accO[i][1] = fmaf(av[i], b4.y, accO[i][1]);
                    accO[i][2] = fmaf(av[i], b4.z, accO[i][2]);
                    accO[i][3] = fmaf(av[i], b4.w, accO[i][3]);
                }
            }
        }
        __syncthreads();   // before next tile overwrites KP/Vs
    }

    #pragma unroll
    for (int i = 0; i < 4; ++i) {
        float inv = 1.f / l_run[i];
        int qi = q0 + ty * 4 + i;
        #pragma unroll
        for (int j = 0; j < 4; ++j)
            o[(size_t)(b * LL + qi) * DD + hh * DH + tx * 4 + j] = accO[i][j] * inv;
    }
}

extern "C" void kernel_launch(void* const* d_in, const int* in_sizes, int n_in,
                              void* d_out, int out_size, void* d_ws, size_t ws_size,
                              hipStream_t stream)
{
    const float* x          = (const float*)d_in[0];
    const int*   lengths    = (const int*)  d_in[1];
    const float* input_delay= (const float*)d_in[2];
    const float* c_local    = (const float*)d_in[3];
    const float* c_sink     = (const float*)d_in[4];
    const float* in_w       = (const float*)d_in[5];
    const float* in_b       = (const float*)d_in[6];
    const float* de_w1      = (const float*)d_in[7];
    const float* de_b1      = (const float*)d_in[8];
    const float* de_w2      = (const float*)d_in[9];
    const float* de_b2      = (const float*)d_in[10];
    const float* de_ln_g    = (const float*)d_in[11];
    const float* de_ln_b    = (const float*)d_in[12];
    const float* cpe_w      = (const float*)d_in[13];
    const float* cpe_b      = (const float*)d_in[14];
    const float* cpe_ln_g   = (const float*)d_in[15];
    const float* cpe_ln_b   = (const float*)d_in[16];
    const float* gain       = (const float*)d_in[17];
    const float* alpha      = (const float*)d_in[18];
    const float* beta       = (const float*)d_in[19];
    const float* floorp     = (const float*)d_in[20];
    const float* gammap     = (const float*)d_in[21];
    const float* inproj_w   = (const float*)d_in[22];
    const float* inproj_b   = (const float*)d_in[23];
    const float* outproj_w  = (const float*)d_in[24];
    const float* outproj_b  = (const float*)d_in[25];
    const float* ln1_g      = (const float*)d_in[26];
    const float* ln1_b      = (const float*)d_in[27];
    const float* ln2_g      = (const float*)d_in[28];
    const float* ln2_b      = (const float*)d_in[29];
    const float* ff_w1      = (const float*)d_in[30];
    const float* ff_b1      = (const float*)d_in[31];
    const float* ff_w2      = (const float*)d_in[32];
    const float* ff_b2      = (const float*)d_in[33];
    const float* out_ln_g   = (const float*)d_in[34];
    const float* out_ln_b   = (const float*)d_in[35];

    const int M = BB * LL;  // 4096
    float* ws  = (float*)d_ws;
    float* h   = ws;                         // M*DD
    float* hn  = h + (size_t)M * DD;         // M*DD  (also reused as attn output)
    float* big = hn + (size_t)M * DD;        // M*DFF (shared by qkv [M*1536] and ff [M*2048])
    float* e   = big + (size_t)M * DFF;      // BB*DD
    float* qkvb = big;
    float* ffb  = big;
    float* ob   = hn;                        // attn out overwrites LN1 output (dead by then)

    delay_kernel<<<BB, 512, 0, stream>>>(input_delay, de_w1, de_b1, de_w2, de_b2, de_ln_g, de_ln_b, e);
    embed_kernel<<<M, 256, 0, stream>>>(x, c_local, c_sink, lengths, in_w, in_b,
                                        cpe_w, cpe_b, cpe_ln_g, cpe_ln_b, gain, e, h);

    for (int i = 0; i < NLAYER; ++i) {
        ln_kernel<<<M, 256, 0, stream>>>(h, hn, ln1_g + (size_t)i * DD, ln1_b + (size_t)i * DD);
        gemm_kernel<<<dim3((3 * DD) / 64, M / 64), 256, 0, stream>>>(
            hn, inproj_w + (size_t)i * 3 * DD * DD, inproj_b + (size_t)i * 3 * DD,
            nullptr, qkvb, M, 3 * DD, DD, 0);
        attn_flash<<<dim3(LL / BQ, HH, BB), 256, 0, stream>>>(qkvb, c_local, c_sink, lengths,
                                                              alpha, beta, floorp, gammap, ob);
        gemm_kernel<<<dim3(DD / 64, M / 64), 256, 0, stream>>>(
            ob, outproj_w + (size_t)i * DD * DD, outproj_b + (size_t)i * DD,
            h, h, M, DD, DD, 0);
        ln_kernel<<<M, 256, 0, stream>>>(h, hn, ln2_g + (size_t)i * DD, ln2_b + (size_t)i * DD);
        gemm_kernel<<<dim3(DFF / 64, M / 64), 256, 0, stream>>>(
            hn, ff_w1 + (size_t)i * DFF * DD, ff_b1 + (size_t)i * DFF,
            nullptr, ffb, M, DFF, DD, 1);
        gemm_kernel<<<dim3(DD / 64, M / 64), 256, 0, stream>>>(
            ffb, ff_w2 + (size_t)i * DD * DFF, ff_b2 + (size_t)i * DD,
            h, h, M, DD, DFF, 0);
    }
    ln_kernel<<<M, 256, 0, stream>>>(h, (float*)d_out, out_ln_g, out_ln_b);
}

// Round 3
// 1769.045 us; speedup vs baseline: 3.4182x; 2.0566x over previous
//
#include <hip/hip_runtime.h>
#include <math.h>

#define BB 4
#define LL 1024
#define DIN 64
#define DD 512
#define HH 8
#define DH 64
#define NLAYER 3
#define DFF 2048
#define FEAT 530
#define FEATP 544
#define MM 4096
#define BQ 64
#define BKT 64

typedef float f32x4 __attribute__((ext_vector_type(4)));
typedef short s16x8 __attribute__((ext_vector_type(8)));

__device__ __forceinline__ unsigned short f2bf(float f) {
    unsigned int u = __float_as_uint(f);
    u += 0x7fffu + ((u >> 16) & 1u);
    return (unsigned short)(u >> 16);
}
__device__ __forceinline__ float gelu_exact(float x) {
    return 0.5f * x * (1.0f + erff(x * 0.7071067811865475f));
}
__device__ __forceinline__ float wave_reduce_sum(float v) {
    #pragma unroll
    for (int o = 32; o; o >>= 1) v += __shfl_down(v, o);
    return v;
}
__device__ __forceinline__ void unpack8(uint4 v, float* f) {
    f[0] = __uint_as_float(v.x << 16); f[1] = __uint_as_float(v.x & 0xffff0000u);
    f[2] = __uint_as_float(v.y << 16); f[3] = __uint_as_float(v.y & 0xffff0000u);
    f[4] = __uint_as_float(v.z << 16); f[5] = __uint_as_float(v.z & 0xffff0000u);
    f[6] = __uint_as_float(v.w << 16); f[7] = __uint_as_float(v.w & 0xffff0000u);
}

// ---------------- generic f32 -> bf16 convert ----------------
__global__ __launch_bounds__(256) void cvt_kernel(
    const float* __restrict__ in, unsigned short* __restrict__ out, int n)
{
    for (int i = blockIdx.x * 256 + threadIdx.x; i < n; i += gridDim.x * 256)
        out[i] = f2bf(in[i]);
}

// ---------------- cpe_w [512][530] f32 -> [512][544] bf16 (zero pad) ----------------
__global__ __launch_bounds__(256) void cpe_pad_kernel(
    const float* __restrict__ in, unsigned short* __restrict__ out)
{
    for (int i = blockIdx.x * 256 + threadIdx.x; i < DD * FEATP; i += gridDim.x * 256) {
        int r = i / FEATP, c = i - r * FEATP;
        out[i] = (c < FEAT) ? f2bf(in[(size_t)r * FEAT + c]) : 0;
    }
}

// ---------------- build Z[M][544] bf16: PE + raw + RBFs ----------------
__global__ __launch_bounds__(256) void build_z_kernel(
    const float* __restrict__ c_local, const float* __restrict__ c_sink,
    unsigned short* __restrict__ Z)
{
    int row = blockIdx.x;
    int b = row >> 10, l = row & 1023;
    int t = threadIdx.x;
    unsigned short* zr = Z + (size_t)row * FEATP;
    for (int d = t; d < DD; d += 256) {
        int i = d >> 1;
        float dv = expf((float)(2 * i) * (-0.017988946135618352f)); // -ln(1e4)/512
        float ang = (float)l * dv;
        zr[d] = f2bf((d & 1) ? cosf(ang) : sinf(ang));
    }
    if (t < 32) {
        float cl = c_local[(size_t)b * LL + l]; cl = fminf(fmaxf(cl, 0.f), 1.f);
        float cs = c_sink [(size_t)b * LL + l]; cs = fminf(fmaxf(cs, 0.f), 1.f);
        float v = 0.f;
        if (t == 0) v = cl;
        else if (t == 1) v = cs;
        else if (t < 10)  { float c = (float)(t - 2) * (1.0f / 7.0f);  float df = (cl - c) / 0.200001f; v = expf(-0.5f * df * df); }
        else if (t < 18)  { float c = (float)(t - 10) * (1.0f / 7.0f); float df = (cs - c) / 0.200001f; v = expf(-0.5f * df * df); }
        zr[512 + t] = (t < 18) ? f2bf(v) : 0;
    }
}

// ---------------- delay feature encoder: e[B,D] ----------------
__global__ __launch_bounds__(512) void delay_kernel(
    const float* __restrict__ delay, const float* __restrict__ w1, const float* __restrict__ b1,
    const float* __restrict__ w2, const float* __restrict__ b2,
    const float* __restrict__ lng, const float* __restrict__ lnb,
    float* __restrict__ e)
{
    int b = blockIdx.x;
    int t = threadIdx.x;
    __shared__ float g1[DD];
    __shared__ float red[16];
    float t1 = delay[b] * w1[t] + b1[t];
    g1[t] = gelu_exact(t1);
    __syncthreads();
    const float* wr = w2 + (size_t)t * DD;
    float s = b2[t];
    for (int j = 0; j < DD; j += 4) {
        float4 w4 = *(const float4*)(wr + j);
        s += w4.x * g1[j] + w4.y * g1[j+1] + w4.z * g1[j+2] + w4.w * g1[j+3];
    }
    float rs = wave_reduce_sum(s);
    float rss = wave_reduce_sum(s * s);
    int lane = t & 63, w = t >> 6;
    if (lane == 0) { red[w] = rs; red[8 + w] = rss; }
    __syncthreads();
    float mean = 0.f, msq = 0.f;
    #pragma unroll
    for (int i = 0; i < 8; ++i) { mean += red[i]; msq += red[8 + i]; }
    mean *= (1.0f / DD); msq *= (1.0f / DD);
    float rstd = rsqrtf(msq - mean * mean + 1e-5f);
    e[(size_t)b * DD + t] = (s - mean) * rstd * lng[t] + lnb[t];
}

// ---- MFMA GEMM: out[M,N] = epilogue(A[M,K]bf16 @ W[N,K]^T bf16 + bias) ----
// mode 0: f32 out = acc+bias ; 1: bf16 out = acc+bias ;
// mode 2: f32 out = acc+bias+resid ; 3: bf16 out = gelu(acc+bias)
__global__ __launch_bounds__(256) void mfma_gemm(
    const unsigned short* __restrict__ A, const unsigned short* __restrict__ W,
    const float* __restrict__ bias, const float* __restrict__ resid,
    float* __restrict__ outf, unsigned short* __restrict__ outb,
    int M, int N, int K, int mode)
{
    __shared__ unsigned short As[128 * 40];   // row stride 40 bf16 = 80 B
    __shared__ unsigned short Ws[128 * 40];
    int bm = blockIdx.y * 128, bn = blockIdx.x * 128;
    int t = threadIdx.x;
    int r = t >> 1, kc = (t & 1) * 16;
    int lane = t & 63, wid = t >> 6;
    int wr = wid >> 1, wc = wid & 1;
    int l15 = lane & 15, q8 = (lane >> 4) * 8;

    f32x4 acc[4][4] = {};
    int nk = K >> 5;
    const unsigned short* ap = A + (size_t)(bm + r) * K + kc;
    const unsigned short* wp = W + (size_t)(bn + r) * K + kc;
    uint4 pa0 = *(const uint4*)ap, pa1 = *(const uint4*)(ap + 8);
    uint4 pw0 = *(const uint4*)wp, pw1 = *(const uint4*)(wp + 8);

    for (int ks = 0; ks < nk; ++ks) {
        *(uint4*)&As[r * 40 + kc]     = pa0;
        *(uint4*)&As[r * 40 + kc + 8] = pa1;
        *(uint4*)&Ws[r * 40 + kc]     = pw0;
        *(uint4*)&Ws[r * 40 + kc + 8] = pw1;
        __syncthreads();
        if (ks + 1 < nk) {
            int off = (ks + 1) * 32;
            pa0 = *(const uint4*)(ap + off); pa1 = *(const uint4*)(ap + off + 8);
            pw0 = *(const uint4*)(wp + off); pw1 = *(const uint4*)(wp + off + 8);
        }
        s16x8 af[4], wf[4];
        #pragma unroll
        for (int mi = 0; mi < 4; ++mi)
            af[mi] = *(const s16x8*)&As[(wr * 64 + mi * 16 + l15) * 40 + q8];
        #pragma unroll
        for (int ni = 0; ni < 4; ++ni)
            wf[ni] = *(const s16x8*)&Ws[(wc * 64 + ni * 16 + l15) * 40 + q8];
        #pragma unroll
        for (int mi = 0; mi < 4; ++mi)
            #pragma unroll
            for (int ni = 0; ni < 4; ++ni)
                acc[mi][ni] = __builtin_amdgcn_mfma_f32_16x16x32_bf16(af[mi], wf[ni], acc[mi][ni], 0, 0, 0);
        __syncthreads();
    }

    int rbase = (lane >> 4) * 4;
    #pragma unroll
    for (int mi = 0; mi < 4; ++mi) {
        #pragma unroll
        for (int ni = 0; ni < 4; ++ni) {
            int n = bn + wc * 64 + ni * 16 + l15;
            float bz = bias[n];
            #pragma unroll
            for (int r2 = 0; r2 < 4; ++r2) {
                int m = bm + wr * 64 + mi * 16 + rbase + r2;
                float v = acc[mi][ni][r2] + bz;
                size_t o = (size_t)m * N + n;
                if (mode == 0)      outf[o] = v;
                else if (mode == 1) outb[o] = f2bf(v);
                else if (mode == 2) outf[o] = v + resid[o];
                else                outb[o] = f2bf(gelu_exact(v));
            }
        }
    }
}

// ------ embed epilogue: h += e + mask?0:gain*LN(cpe_pre) ------
__global__ __launch_bounds__(256) void embed_ep_kernel(
    const float* __restrict__ cpe_pre, const float* __restrict__ e,
    const int* __restrict__ lengths,
    const float* __restrict__ cpe_g, const float* __restrict__ cpe_lb,
    const float* __restrict__ gain_p, float* __restrict__ h)
{
    int row = blockIdx.x;
    int b = row >> 10, l = row & 1023;
    int t = threadIdx.x;
    __shared__ float red[16];
    const float* cp = cpe_pre + (size_t)row * DD;
    float v0 = cp[t], v1 = cp[t + 256];
    float s = v0 + v1, ss = v0 * v0 + v1 * v1;
    float rs = wave_reduce_sum(s), rss = wave_reduce_sum(ss);
    int lane = t & 63, w = t >> 6;
    if (lane == 0) { red[w] = rs; red[8 + w] = rss; }
    __syncthreads();
    float mean = 0.f, msq = 0.f;
    #pragma unroll
    for (int i = 0; i < 4; ++i) { mean += red[i]; msq += red[8 + i]; }
    mean *= (1.0f / DD); msq *= (1.0f / DD);
    float rstd = rsqrtf(msq - mean * mean + 1e-5f);
    bool maskp = (l >= lengths[b]);
    float gain = *gain_p;
    float pe0 = maskp ? 0.f : gain * ((v0 - mean) * rstd * cpe_g[t] + cpe_lb[t]);
    float pe1 = maskp ? 0.f : gain * ((v1 - mean) * rstd * cpe_g[t + 256] + cpe_lb[t + 256]);
    h[(size_t)row * DD + t]       += e[(size_t)b * DD + t] + pe0;
    h[(size_t)row * DD + t + 256] += e[(size_t)b * DD + t + 256] + pe1;
}

// ---------------- LayerNorm f32 out (final) ----------------
__global__ __launch_bounds__(256) void ln_kernel(
    const float* __restrict__ in, float* __restrict__ out,
    const float* __restrict__ g, const float* __restrict__ bta)
{
    int row = blockIdx.x; int t = threadIdx.x;
    __shared__ float red[16];
    const float* xr = in + (size_t)row * DD;
    float2 v = ((const float2*)xr)[t];
    float s = v.x + v.y, ss = v.x * v.x + v.y * v.y;
    float rs = wave_reduce_sum(s), rss = wave_reduce_sum(ss);
    int lane = t & 63, w = t >> 6;
    if (lane == 0) { red[w] = rs; red[8 + w] = rss; }
    __syncthreads();
    float mean = 0.f, msq = 0.f;
    #pragma unroll
    for (int i = 0; i < 4; ++i) { mean += red[i]; msq += red[8 + i]; }
    mean *= (1.0f / DD); msq *= (1.0f / DD);
    float rstd = rsqrtf(msq - mean * mean + 1e-5f);
    float2 gg = ((const float2*)g)[t], bb = ((const float2*)bta)[t];
    float2 o;
    o.x = (v.x - mean) * rstd * gg.x + bb.x;
    o.y = (v.y - mean) * rstd * gg.y + bb.y;
    ((float2*)(out + (size_t)row * DD))[t] = o;
}

// ---------------- LayerNorm bf16 out ----------------
__global__ __launch_bounds__(256) void ln_bf16_kernel(
    const float* __restrict__ in, unsigned short* __restrict__ out,
    const float* __restrict__ g, const float* __restrict__ bta)
{
    int row = blockIdx.x; int t = threadIdx.x;
    __shared__ float red[16];
    const float* xr = in + (size_t)row * DD;
    float2 v = ((const float2*)xr)[t];
    float s = v.x + v.y, ss = v.x * v.x + v.y * v.y;
    float rs = wave_reduce_sum(s), rss = wave_reduce_sum(ss);
    int lane = t & 63, w = t >> 6;
    if (lane == 0) { red[w] = rs; red[8 + w] = rss; }
    __syncthreads();
    float mean = 0.f, msq = 0.f;
    #pragma unroll
    for (int i = 0; i < 4; ++i) { mean += red[i]; msq += red[8 + i]; }
    mean *= (1.0f / DD); msq *= (1.0f / DD);
    float rstd = rsqrtf(msq - mean * mean + 1e-5f);
    float2 gg = ((const float2*)g)[t], bb = ((const float2*)bta)[t];
    ushort2 o;
    o.x = f2bf((v.x - mean) * rstd * gg.x + bb.x);
    o.y = f2bf((v.y - mean) * rstd * gg.y + bb.y);
    ((ushort2*)(out + (size_t)row * DD))[t] = o;
}

// ------------- flash attention (bf16 qkv in, bf16 out) -------------
__global__ __launch_bounds__(256) void attn_flash(
    const unsigned short* __restrict__ qkv,
    const float* __restrict__ c_local, const float* __restrict__ c_sink,
    const int* __restrict__ lengths,
    const float* __restrict__ alpha_p, const float* __restrict__ beta_p,
    const float* __restrict__ floor_p, const float* __restrict__ gamma_p,
    unsigned short* __restrict__ o)
{
    __shared__ float Qs[BQ][DH + 4];
    __shared__ float KP[BKT][DH + 4];   // K tile (swizzled), reused for P (linear)
    __shared__ float Vs[BKT][DH + 4];   // V tile (swizzled)

    int q0 = blockIdx.x * BQ;
    int hh = blockIdx.y;
    int b  = blockIdx.z;
    int t  = threadIdx.x;
    int tx = t & 15, ty = t >> 4;
    int len = lengths[b];
    const float alpha = *alpha_p, beta = *beta_p, flr = *floor_p, gmm = *gamma_p;

    // load Q tile (linear layout)
    #pragma unroll
    for (int u = 0; u < 2; ++u) {
        int idx = t + 256 * u;
        int r = idx >> 3, c8 = idx & 7;
        uint4 qv = *(const uint4*)(qkv + (size_t)(b * LL + q0 + r) * 1536 + hh * DH + c8 * 8);
        float f[8]; unpack8(qv, f);
        *(float4*)&Qs[r][c8 * 8]     = make_float4(f[0], f[1], f[2], f[3]);
        *(float4*)&Qs[r][c8 * 8 + 4] = make_float4(f[4], f[5], f[6], f[7]);
    }

    float m_run[4], l_run[4], accO[4][4] = {};
    #pragma unroll
    for (int i = 0; i < 4; ++i) { m_run[i] = -1e30f; l_run[i] = 0.f; }

    for (int k0 = 0; k0 < LL; k0 += BKT) {
        #pragma unroll
        for (int u = 0; u < 2; ++u) {
            int idx = t + 256 * u;
            int r = idx >> 3, c8 = idx & 7;
            size_t rowb = (size_t)(b * LL + k0 + r) * 1536 + hh * DH + c8 * 8;
            uint4 kv = *(const uint4*)(qkv + rowb + 512);
            uint4 vv = *(const uint4*)(qkv + rowb + 1024);
            float fk[8], fv[8]; unpack8(kv, fk); unpack8(vv, fv);
            int swz = (r >> 2) & 7;
            int sa = (2 * c8) ^ swz, sb = (2 * c8 + 1) ^ swz;
            *(float4*)&KP[r][sa * 4] = make_float4(fk[0], fk[1], fk[2], fk[3]);
            *(float4*)&KP[r][sb * 4] = make_float4(fk[4], fk[5], fk[6], fk[7]);
            *(float4*)&Vs[r][sa * 4] = make_float4(fv[0], fv[1], fv[2], fv[3]);
            *(float4*)&Vs[r][sb * 4] = make_float4(fv[4], fv[5], fv[6], fv[7]);
        }
        __syncthreads();

        // S = Q K^T (register 4x4 tile)
        float s[4][4] = {};
        #pragma unroll
        for (int d4 = 0; d4 < 16; ++d4) {
            float4 a4[4], b4[4];
            #pragma unroll
            for (int i = 0; i < 4; ++i) a4[i] = *(const float4*)&Qs[ty * 4 + i][d4 * 4];
            #pragma unroll
            for (int j = 0; j < 4; ++j) {
                int rr = tx * 4 + j;
                b4[j] = *(const float4*)&KP[rr][(d4 ^ ((rr >> 2) & 7)) * 4];
            }
            #pragma unroll
            for (int i = 0; i < 4; ++i)
                #pragma unroll
                for (int j = 0; j < 4; ++j) {
                    s[i][j] = fmaf(a4[i].x, b4[j].x, s[i][j]);
                    s[i][j] = fmaf(a4[i].y, b4[j].y, s[i][j]);
                    s[i][j] = fmaf(a4[i].z, b4[j].z, s[i][j]);
                    s[i][j] = fmaf(a4[i].w, b4[j].w, s[i][j]);
                }
        }
        __syncthreads();

        // bias + mask + online softmax; write P into KP (linear)
        #pragma unroll
        for (int i = 0; i < 4; ++i) {
            int qi = q0 + ty * 4 + i;
            bool maskq = (qi >= len);
            float tm = -1e30f;
            #pragma unroll
            for (int j = 0; j < 4; ++j) {
                int kj = k0 + tx * 4 + j;
                float v = s[i][j] * 0.125f;
                bool maskk = (kj >= len);
                if (!maskq && !maskk) {
                    if (kj == qi - 1) {
                        float cval = (qi == 1 || qi == LL - 1) ? c_local[(size_t)b * LL + qi]
                                                               : c_local[(size_t)b * LL + qi - 1];
                        v += alpha * cval;
                    } else if (kj == qi + 1) {
                        v += alpha * c_local[(size_t)b * LL + qi + 1];
                    }
                }
                if (qi == 0 && !maskk) {
                    float csv = c_sink[(size_t)b * LL + kj];
                    csv = fminf(fmaxf(csv, 0.f), 1.f);
                    v += beta * (flr + (1.f - flr) * powf(csv + 1e-6f, gmm));
                }
                if (maskk) v -= 10000.f;
                s[i][j] = v;
                tm = fmaxf(tm, v);
            }
            #pragma unroll
            for (int msk = 1; msk < 16; msk <<= 1) tm = fmaxf(tm, __shfl_xor(tm, msk));
            float mnew = fmaxf(m_run[i], tm);
            float scl = __expf(m_run[i] - mnew);
            float rowsum = 0.f;
            #pragma unroll
            for (int j = 0; j < 4; ++j) {
                float p = __expf(s[i][j] - mnew);
                s[i][j] = p;
                rowsum += p;
            }
            #pragma unroll
            for (int msk = 1; msk < 16; msk <<= 1) rowsum += __shfl_xor(rowsum, msk);
            l_run[i] = l_run[i] * scl + rowsum;
            m_run[i] = mnew;
            #pragma unroll
            for (int j = 0; j < 4; ++j) {
                accO[i][j] *= scl;
                KP[ty * 4 + i][tx * 4 + j] = s[i][j];
            }
        }
        __syncthreads();

        // O += P @ V
        #pragma unroll
        for (int k4 = 0; k4 < 16; ++k4) {
            float4 a4[4];
            #pragma unroll
            for (int i = 0; i < 4; ++i) a4[i] = *(const float4*)&KP[ty * 4 + i][k4 * 4];
            #pragma unroll
            for (int kk = 0; kk < 4; ++kk) {
                float4 b4 = *(const float4*)&Vs[k4 * 4 + kk][(tx ^ (k4 & 7)) * 4];
                float av[4] = { a4[0].x, a4[1].x, a4[2].x, a4[3].x };
                if (kk == 1) { av[0] = a4[0].y; av[1] = a4[1].y; av[2] = a4[2].y; av[3] = a4[3].y; }
                if (kk == 2) { av[0] = a4[0].z; av[1] = a4[1].z; av[2] = a4[2].z; av[3] = a4[3].z; }
                if (kk == 3) { av[0] = a4[0].w; av[1] = a4[1].w; av[2] = a4[2].w; av[3] = a4[3].w; }
                #pragma unroll
                for (int i = 0; i < 4; ++i) {
                    accO[i][0] = fmaf(av[i], b4.x, accO[i][0]);
                    accO[i][1] = fmaf(av[i], b4.y, accO[i][1]);
                    accO[i][2] = fmaf(av[i], b4.z, accO[i][2]);
                    accO[i][3] = fmaf(av[i], b4.w, accO[i][3]);
                }
            }
        }
        __syncthreads();
    }

    #pragma unroll
    for (int i = 0; i < 4; ++i) {
        float inv = 1.f / l_run[i];
        int qi = q0 + ty * 4 + i;
        #pragma unroll
        for (int j = 0; j < 4; ++j)
            o[(size_t)(b * LL + qi) * DD + hh * DH + tx * 4 + j] = f2bf(accO[i][j] * inv);
    }
}

extern "C" void kernel_launch(void* const* d_in, const int* in_sizes, int n_in,
                              void* d_out, int out_size, void* d_ws, size_t ws_size,
                              hipStream_t stream)
{
    const float* x          = (const float*)d_in[0];
    const int*   lengths    = (const int*)  d_in[1];
    const float* input_delay= (const float*)d_in[2];
    const float* c_local    = (const float*)d_in[3];
    const float* c_sink     = (const float*)d_in[4];
    const float* in_w       = (const float*)d_in[5];
    const float* in_b       = (const float*)d_in[6];
    const float* de_w1      = (const float*)d_in[7];
    const float* de_b1      = (const float*)d_in[8];
    const float* de_w2      = (const float*)d_in[9];
    const float* de_b2      = (const float*)d_in[10];
    const float* de_ln_g    = (const float*)d_in[11];
    const float* de_ln_b    = (const float*)d_in[12];
    const float* cpe_w      = (const float*)d_in[13];
    const float* cpe_b      = (const float*)d_in[14];
    const float* cpe_ln_g   = (const float*)d_in[15];
    const float* cpe_ln_b   = (const float*)d_in[16];
    const float* gain       = (const float*)d_in[17];
    const float* alpha      = (const float*)d_in[18];
    const float* beta       = (const float*)d_in[19];
    const float* floorp     = (const float*)d_in[20];
    const float* gammap     = (const float*)d_in[21];
    const float* inproj_w   = (const float*)d_in[22];
    const float* inproj_b   = (const float*)d_in[23];
    const float* outproj_w  = (const float*)d_in[24];
    const float* outproj_b  = (const float*)d_in[25];
    const float* ln1_g      = (const float*)d_in[26];
    const float* ln1_b      = (const float*)d_in[27];
    const float* ln2_g      = (const float*)d_in[28];
    const float* ln2_b      = (const float*)d_in[29];
    const float* ff_w1      = (const float*)d_in[30];
    const float* ff_b1      = (const float*)d_in[31];
    const float* ff_w2      = (const float*)d_in[32];
    const float* ff_b2      = (const float*)d_in[33];
    const float* out_ln_g   = (const float*)d_in[34];
    const float* out_ln_b   = (const float*)d_in[35];

    char* base = (char*)d_ws;
    float* h            = (float*)base;                               // 8 MB
    unsigned short* act1 = (unsigned short*)(base + 8u*1024*1024);    // 4 MB
    char* bigb          = base + 12u*1024*1024;                       // 16 MB shared region
    unsigned short* qkvb = (unsigned short*)bigb;                     // 12 MB (attn phase)
    unsigned short* ffb  = (unsigned short*)bigb;                     // 16 MB (FF phase)
    unsigned short* Zb   = (unsigned short*)bigb;                     // 4.46 MB (embed phase)
    unsigned short* x_bf = (unsigned short*)(bigb + 5u*1024*1024);    // 0.5 MB
    float* cpe_pre       = (float*)(bigb + 8u*1024*1024);             // 8 MB
    unsigned short* w_inproj  = (unsigned short*)(base + 28u*1024*1024);
    unsigned short* w_outproj = w_inproj  + (size_t)3*1536*512;
    unsigned short* w_ff1     = w_outproj + (size_t)3*512*512;
    unsigned short* w_ff2     = w_ff1     + (size_t)3*2048*512;
    unsigned short* w_in      = w_ff2     + (size_t)3*512*2048;
    unsigned short* w_cpe     = w_in      + (size_t)512*64;
    float* e                  = (float*)(w_cpe + (size_t)512*544);

    // weight / input conversions (every launch; deterministic)
    cvt_kernel<<<128, 256, 0, stream>>>(x, x_bf, MM * DIN);
    cvt_kernel<<<2048, 256, 0, stream>>>(inproj_w, w_inproj, 3 * 1536 * 512);
    cvt_kernel<<<1024, 256, 0, stream>>>(outproj_w, w_outproj, 3 * 512 * 512);
    cvt_kernel<<<2048, 256, 0, stream>>>(ff_w1, w_ff1, 3 * 2048 * 512);
    cvt_kernel<<<2048, 256, 0, stream>>>(ff_w2, w_ff2, 3 * 512 * 2048);
    cvt_kernel<<<64, 256, 0, stream>>>(in_w, w_in, 512 * 64);
    cpe_pad_kernel<<<1024, 256, 0, stream>>>(cpe_w, w_cpe);

    delay_kernel<<<BB, 512, 0, stream>>>(input_delay, de_w1, de_b1, de_w2, de_b2, de_ln_g, de_ln_b, e);
    build_z_kernel<<<MM, 256, 0, stream>>>(c_local, c_sink, Zb);

    // h0 = x @ in_w^T + in_b
    mfma_gemm<<<dim3(DD / 128, MM / 128), 256, 0, stream>>>(
        x_bf, w_in, in_b, nullptr, h, nullptr, MM, DD, DIN, 0);
    // cpe_pre = Z @ cpe_w^T + cpe_b
    mfma_gemm<<<dim3(DD / 128, MM / 128), 256, 0, stream>>>(
        Zb, w_cpe, cpe_b, nullptr, cpe_pre, nullptr, MM, DD, FEATP, 0);
    embed_ep_kernel<<<MM, 256, 0, stream>>>(cpe_pre, e, lengths, cpe_ln_g, cpe_ln_b, gain, h);

    for (int i = 0; i < NLAYER; ++i) {
        ln_bf16_kernel<<<MM, 256, 0, stream>>>(h, act1, ln1_g + (size_t)i * DD, ln1_b + (size_t)i * DD);
        mfma_gemm<<<dim3(1536 / 128, MM / 128), 256, 0, stream>>>(
            act1, w_inproj + (size_t)i * 1536 * 512, inproj_b + (size_t)i * 1536,
            nullptr, nullptr, qkvb, MM, 1536, DD, 1);
        attn_flash<<<dim3(LL / BQ, HH, BB), 256, 0, stream>>>(qkvb, c_local, c_sink, lengths,
                                                              alpha, beta, floorp, gammap, act1);
        mfma_gemm<<<dim3(DD / 128, MM / 128), 256, 0, stream>>>(
            act1, w_outproj + (size_t)i * 512 * 512, outproj_b + (size_t)i * DD,
            h, h, nullptr, MM, DD, DD, 2);
        ln_bf16_kernel<<<MM, 256, 0, stream>>>(h, act1, ln2_g + (size_t)i * DD, ln2_b + (size_t)i * DD);
        mfma_gemm<<<dim3(DFF / 128, MM / 128), 256, 0, stream>>>(
            act1, w_ff1 + (size_t)i * 2048 * 512, ff_b1 + (size_t)i * DFF,
            nullptr, nullptr, ffb, MM, DFF, DD, 3);
        mfma_gemm<<<dim3(DD / 128, MM / 128), 256, 0, stream>>>(
            ffb, w_ff2 + (size_t)i * 512 * 2048, ff_b2 + (size_t)i * DD,
            h, h, nullptr, MM, DD, DFF, 2);
    }
    ln_kernel<<<MM, 256, 0, stream>>>(h, (float*)d_out, out_ln_g, out_ln_b);
}

// Round 4
// 760.815 us; speedup vs baseline: 7.9480x; 2.3252x over previous
//
#include <hip/hip_runtime.h>
#include <math.h>

#define BB 4
#define LL 1024
#define DIN 64
#define DD 512
#define HH 8
#define DH 64
#define NLAYER 3
#define DFF 2048
#define FEAT 530
#define FEATP 544
#define MM 4096

typedef float f32x4 __attribute__((ext_vector_type(4)));
typedef short s16x8 __attribute__((ext_vector_type(8)));

__device__ __forceinline__ unsigned short f2bf(float f) {
    unsigned int u = __float_as_uint(f);
    u += 0x7fffu + ((u >> 16) & 1u);
    return (unsigned short)(u >> 16);
}
__device__ __forceinline__ float gelu_exact(float x) {
    return 0.5f * x * (1.0f + erff(x * 0.7071067811865475f));
}
__device__ __forceinline__ float wave_reduce_sum(float v) {
    #pragma unroll
    for (int o = 32; o; o >>= 1) v += __shfl_down(v, o);
    return v;
}

// ---------------- generic f32 -> bf16 convert ----------------
__global__ __launch_bounds__(256) void cvt_kernel(
    const float* __restrict__ in, unsigned short* __restrict__ out, int n)
{
    for (int i = blockIdx.x * 256 + threadIdx.x; i < n; i += gridDim.x * 256)
        out[i] = f2bf(in[i]);
}

// ---------------- cpe_w [512][530] f32 -> [512][544] bf16 (zero pad) ----------------
__global__ __launch_bounds__(256) void cpe_pad_kernel(
    const float* __restrict__ in, unsigned short* __restrict__ out)
{
    for (int i = blockIdx.x * 256 + threadIdx.x; i < DD * FEATP; i += gridDim.x * 256) {
        int r = i / FEATP, c = i - r * FEATP;
        out[i] = (c < FEAT) ? f2bf(in[(size_t)r * FEAT + c]) : 0;
    }
}

// ---------------- build Z[M][544] bf16: PE + raw + RBFs ----------------
__global__ __launch_bounds__(256) void build_z_kernel(
    const float* __restrict__ c_local, const float* __restrict__ c_sink,
    unsigned short* __restrict__ Z)
{
    int row = blockIdx.x;
    int b = row >> 10, l = row & 1023;
    int t = threadIdx.x;
    unsigned short* zr = Z + (size_t)row * FEATP;
    for (int d = t; d < DD; d += 256) {
        int i = d >> 1;
        float dv = expf((float)(2 * i) * (-0.017988946135618352f)); // -ln(1e4)/512
        float ang = (float)l * dv;
        zr[d] = f2bf((d & 1) ? cosf(ang) : sinf(ang));
    }
    if (t < 32) {
        float cl = c_local[(size_t)b * LL + l]; cl = fminf(fmaxf(cl, 0.f), 1.f);
        float cs = c_sink [(size_t)b * LL + l]; cs = fminf(fmaxf(cs, 0.f), 1.f);
        float v = 0.f;
        if (t == 0) v = cl;
        else if (t == 1) v = cs;
        else if (t < 10)  { float c = (float)(t - 2) * (1.0f / 7.0f);  float df = (cl - c) / 0.200001f; v = expf(-0.5f * df * df); }
        else if (t < 18)  { float c = (float)(t - 10) * (1.0f / 7.0f); float df = (cs - c) / 0.200001f; v = expf(-0.5f * df * df); }
        zr[512 + t] = (t < 18) ? f2bf(v) : 0;
    }
}

// ---------------- delay feature encoder: e[B,D] ----------------
__global__ __launch_bounds__(512) void delay_kernel(
    const float* __restrict__ delay, const float* __restrict__ w1, const float* __restrict__ b1,
    const float* __restrict__ w2, const float* __restrict__ b2,
    const float* __restrict__ lng, const float* __restrict__ lnb,
    float* __restrict__ e)
{
    int b = blockIdx.x;
    int t = threadIdx.x;
    __shared__ float g1[DD];
    __shared__ float red[16];
    float t1 = delay[b] * w1[t] + b1[t];
    g1[t] = gelu_exact(t1);
    __syncthreads();
    const float* wr = w2 + (size_t)t * DD;
    float s = b2[t];
    for (int j = 0; j < DD; j += 4) {
        float4 w4 = *(const float4*)(wr + j);
        s += w4.x * g1[j] + w4.y * g1[j+1] + w4.z * g1[j+2] + w4.w * g1[j+3];
    }
    float rs = wave_reduce_sum(s);
    float rss = wave_reduce_sum(s * s);
    int lane = t & 63, w = t >> 6;
    if (lane == 0) { red[w] = rs; red[8 + w] = rss; }
    __syncthreads();
    float mean = 0.f, msq = 0.f;
    #pragma unroll
    for (int i = 0; i < 8; ++i) { mean += red[i]; msq += red[8 + i]; }
    mean *= (1.0f / DD); msq *= (1.0f / DD);
    float rstd = rsqrtf(msq - mean * mean + 1e-5f);
    e[(size_t)b * DD + t] = (s - mean) * rstd * lng[t] + lnb[t];
}

// ---- MFMA GEMM: out[M,N] = epilogue(A[M,K]bf16 @ W[N,K]^T bf16 + bias) ----
// mode 0: f32 out = acc+bias ; 1: bf16 out = acc+bias ;
// mode 2: f32 out = acc+bias+resid ; 3: bf16 out = gelu(acc+bias)
__global__ __launch_bounds__(256) void mfma_gemm(
    const unsigned short* __restrict__ A, const unsigned short* __restrict__ W,
    const float* __restrict__ bias, const float* __restrict__ resid,
    float* __restrict__ outf, unsigned short* __restrict__ outb,
    int M, int N, int K, int mode)
{
    __shared__ unsigned short As[128 * 40];   // row stride 40 bf16 = 80 B
    __shared__ unsigned short Ws[128 * 40];
    int bm = blockIdx.y * 128, bn = blockIdx.x * 128;
    int t = threadIdx.x;
    int r = t >> 1, kc = (t & 1) * 16;
    int lane = t & 63, wid = t >> 6;
    int wr = wid >> 1, wc = wid & 1;
    int l15 = lane & 15, q8 = (lane >> 4) * 8;

    f32x4 acc[4][4] = {};
    int nk = K >> 5;
    const unsigned short* ap = A + (size_t)(bm + r) * K + kc;
    const unsigned short* wp = W + (size_t)(bn + r) * K + kc;
    uint4 pa0 = *(const uint4*)ap, pa1 = *(const uint4*)(ap + 8);
    uint4 pw0 = *(const uint4*)wp, pw1 = *(const uint4*)(wp + 8);

    for (int ks = 0; ks < nk; ++ks) {
        *(uint4*)&As[r * 40 + kc]     = pa0;
        *(uint4*)&As[r * 40 + kc + 8] = pa1;
        *(uint4*)&Ws[r * 40 + kc]     = pw0;
        *(uint4*)&Ws[r * 40 + kc + 8] = pw1;
        __syncthreads();
        if (ks + 1 < nk) {
            int off = (ks + 1) * 32;
            pa0 = *(const uint4*)(ap + off); pa1 = *(const uint4*)(ap + off + 8);
            pw0 = *(const uint4*)(wp + off); pw1 = *(const uint4*)(wp + off + 8);
        }
        s16x8 af[4], wf[4];
        #pragma unroll
        for (int mi = 0; mi < 4; ++mi)
            af[mi] = *(const s16x8*)&As[(wr * 64 + mi * 16 + l15) * 40 + q8];
        #pragma unroll
        for (int ni = 0; ni < 4; ++ni)
            wf[ni] = *(const s16x8*)&Ws[(wc * 64 + ni * 16 + l15) * 40 + q8];
        #pragma unroll
        for (int mi = 0; mi < 4; ++mi)
            #pragma unroll
            for (int ni = 0; ni < 4; ++ni)
                acc[mi][ni] = __builtin_amdgcn_mfma_f32_16x16x32_bf16(af[mi], wf[ni], acc[mi][ni], 0, 0, 0);
        __syncthreads();
    }

    int rbase = (lane >> 4) * 4;
    #pragma unroll
    for (int mi = 0; mi < 4; ++mi) {
        #pragma unroll
        for (int ni = 0; ni < 4; ++ni) {
            int n = bn + wc * 64 + ni * 16 + l15;
            float bz = bias[n];
            #pragma unroll
            for (int r2 = 0; r2 < 4; ++r2) {
                int m = bm + wr * 64 + mi * 16 + rbase + r2;
                float v = acc[mi][ni][r2] + bz;
                size_t o = (size_t)m * N + n;
                if (mode == 0)      outf[o] = v;
                else if (mode == 1) outb[o] = f2bf(v);
                else if (mode == 2) outf[o] = v + resid[o];
                else                outb[o] = f2bf(gelu_exact(v));
            }
        }
    }
}

// ---- V transpose: qkv V part -> Vt[b][h][d][l] ----
__global__ __launch_bounds__(256) void vtrans_kernel(
    const unsigned short* __restrict__ qkv, unsigned short* __restrict__ Vt)
{
    __shared__ unsigned short Ts[64 * 68];
    int l0 = blockIdx.x * 64;
    int hh = blockIdx.y;
    int b  = blockIdx.z;
    int t  = threadIdx.x;
    #pragma unroll
    for (int u = 0; u < 2; ++u) {
        int idx = t + u * 256;
        int r = idx >> 3, c8 = idx & 7;
        uint4 v = *(const uint4*)(qkv + (size_t)(b * LL + l0 + r) * 1536 + 1024 + hh * DH + c8 * 8);
        *(uint4*)&Ts[r * 68 + c8 * 8] = v;
    }
    __syncthreads();
    #pragma unroll
    for (int u = 0; u < 2; ++u) {
        int d = (t >> 3) + u * 32;
        int c = t & 7;
        unsigned short tmp[8];
        #pragma unroll
        for (int j = 0; j < 8; ++j) tmp[j] = Ts[(c * 8 + j) * 68 + d];
        *(uint4*)(Vt + ((size_t)((b * HH + hh) * DH + d)) * LL + l0 + c * 8) = *(const uint4*)tmp;
    }
}

// ------------- MFMA flash attention: block = (b, h, 64-q tile), 4 waves -------------
#define SK 72
#define SP 68
__global__ __launch_bounds__(256) void attn_mfma(
    const unsigned short* __restrict__ qkv, const unsigned short* __restrict__ Vt,
    const float* __restrict__ c_local, const float* __restrict__ c_sink,
    const int* __restrict__ lengths,
    const float* __restrict__ alpha_p, const float* __restrict__ beta_p,
    const float* __restrict__ floor_p, const float* __restrict__ gamma_p,
    unsigned short* __restrict__ o)
{
    __shared__ __align__(16) unsigned short Ks[64 * SK];
    __shared__ __align__(16) unsigned short Vts[64 * SK];
    __shared__ __align__(16) float Ps[64 * SP];

    int q0 = blockIdx.x * 64;
    int hh = blockIdx.y;
    int b  = blockIdx.z;
    int t  = threadIdx.x;
    int lane = t & 63, w = t >> 6;
    int l15 = lane & 15, lg = lane >> 4;
    int len = lengths[b];
    const float alpha = *alpha_p, beta = *beta_p, flr = *floor_p, gmm = *gamma_p;

    // Q fragments (2 k-steps), rows = q0 + w*16 + l15
    const unsigned short* qrow = qkv + (size_t)(b * LL + q0 + w * 16 + l15) * 1536 + hh * DH;
    s16x8 qf0 = *(const s16x8*)(qrow + lg * 8);
    s16x8 qf1 = *(const s16x8*)(qrow + 32 + lg * 8);

    // per-row bias precompute (rows q0 + w*16 + lg*4 + r)
    float cm1[4], cp1[4];
    bool  isq0[4];
    #pragma unroll
    for (int r2 = 0; r2 < 4; ++r2) {
        int qi = q0 + w * 16 + lg * 4 + r2;
        cm1[r2] = 0.f; cp1[r2] = 0.f;
        isq0[r2] = (qi == 0);
        if (qi >= 1 && qi < len) {
            int src = (qi == 1 || qi == LL - 1) ? qi : qi - 1;
            cm1[r2] = alpha * c_local[(size_t)b * LL + src];
        }
        if (qi + 1 < LL && qi < len)
            cp1[r2] = alpha * c_local[(size_t)b * LL + qi + 1];
    }

    float m_run[4], l_run[4];
    f32x4 accO[4] = {};
    #pragma unroll
    for (int r2 = 0; r2 < 4; ++r2) { m_run[r2] = -1e30f; l_run[r2] = 0.f; }

    // staging assignment: idx = t + u*256 -> r = idx>>3, c8 = idx&7
    int sr = t >> 3, sc8 = (t & 7) * 8;
    const unsigned short* kbase = qkv + (size_t)(b * LL) * 1536 + 512 + hh * DH;
    const unsigned short* vbase = Vt + ((size_t)((b * HH + hh) * DH)) * LL;

    // prefetch tile 0
    uint4 pk0 = *(const uint4*)(kbase + (size_t)sr * 1536 + sc8);
    uint4 pk1 = *(const uint4*)(kbase + (size_t)(sr + 32) * 1536 + sc8);
    uint4 pv0 = *(const uint4*)(vbase + (size_t)sr * LL + sc8);
    uint4 pv1 = *(const uint4*)(vbase + (size_t)(sr + 32) * LL + sc8);

    for (int k0 = 0; k0 < LL; k0 += 64) {
        *(uint4*)&Ks[sr * SK + sc8]         = pk0;
        *(uint4*)&Ks[(sr + 32) * SK + sc8]  = pk1;
        *(uint4*)&Vts[sr * SK + sc8]        = pv0;
        *(uint4*)&Vts[(sr + 32) * SK + sc8] = pv1;
        if (k0 + 64 < LL) {
            pk0 = *(const uint4*)(kbase + (size_t)(k0 + 64 + sr) * 1536 + sc8);
            pk1 = *(const uint4*)(kbase + (size_t)(k0 + 64 + sr + 32) * 1536 + sc8);
            pv0 = *(const uint4*)(vbase + (size_t)sr * LL + k0 + 64 + sc8);
            pv1 = *(const uint4*)(vbase + (size_t)(sr + 32) * LL + k0 + 64 + sc8);
        }
        __syncthreads();

        // S = Q K^T : accS[ct] covers cols ct*16..+15
        f32x4 accS[4] = {};
        #pragma unroll
        for (int ct = 0; ct < 4; ++ct) {
            s16x8 kf0 = *(const s16x8*)&Ks[(ct * 16 + l15) * SK + lg * 8];
            s16x8 kf1 = *(const s16x8*)&Ks[(ct * 16 + l15) * SK + 32 + lg * 8];
            accS[ct] = __builtin_amdgcn_mfma_f32_16x16x32_bf16(qf0, kf0, accS[ct], 0, 0, 0);
            accS[ct] = __builtin_amdgcn_mfma_f32_16x16x32_bf16(qf1, kf1, accS[ct], 0, 0, 0);
        }

        // bias + mask, row stats, online update, P -> LDS
        float m4[4] = { -1e30f, -1e30f, -1e30f, -1e30f };
        #pragma unroll
        for (int ct = 0; ct < 4; ++ct) {
            int k = k0 + ct * 16 + l15;
            bool maskk = (k >= len);
            float sink = 0.f;
            if (!maskk) {
                float csv = c_sink[(size_t)b * LL + k];
                csv = fminf(fmaxf(csv, 0.f), 1.f);
                sink = beta * (flr + (1.f - flr) * powf(csv + 1e-6f, gmm));
            }
            #pragma unroll
            for (int r2 = 0; r2 < 4; ++r2) {
                int qi = q0 + w * 16 + lg * 4 + r2;
                float v = accS[ct][r2] * 0.125f;
                if (k == qi - 1) v += cm1[r2];
                else if (k == qi + 1 && !maskk) v += cp1[r2];
                if (isq0[r2]) v += sink;
                if (maskk) v -= 10000.f;
                accS[ct][r2] = v;
                m4[r2] = fmaxf(m4[r2], v);
            }
        }
        #pragma unroll
        for (int r2 = 0; r2 < 4; ++r2) {
            #pragma unroll
            for (int msk = 1; msk < 16; msk <<= 1) m4[r2] = fmaxf(m4[r2], __shfl_xor(m4[r2], msk));
            float mnew = fmaxf(m_run[r2], m4[r2]);
            float scl = __expf(m_run[r2] - mnew);
            m_run[r2] = mnew;
            float rowsum = 0.f;
            #pragma unroll
            for (int ct = 0; ct < 4; ++ct) {
                float p = __expf(accS[ct][r2] - mnew);
                accS[ct][r2] = p;
                rowsum += p;
            }
            #pragma unroll
            for (int msk = 1; msk < 16; msk <<= 1) rowsum += __shfl_xor(rowsum, msk);
            l_run[r2] = l_run[r2] * scl + rowsum;
            #pragma unroll
            for (int dt = 0; dt < 4; ++dt) accO[dt][r2] *= scl;
            #pragma unroll
            for (int ct = 0; ct < 4; ++ct)
                Ps[(w * 16 + lg * 4 + r2) * SP + ct * 16 + l15] = accS[ct][r2];
        }

        // O += P @ V  (A-frags from Ps rows of this wave; B-frags from Vts)
        #pragma unroll
        for (int kk = 0; kk < 2; ++kk) {
            const float* pr = &Ps[(w * 16 + l15) * SP + kk * 32 + lg * 8];
            s16x8 pf;
            #pragma unroll
            for (int j = 0; j < 8; ++j) pf[j] = (short)f2bf(pr[j]);
            #pragma unroll
            for (int dt = 0; dt < 4; ++dt) {
                s16x8 vf = *(const s16x8*)&Vts[(dt * 16 + l15) * SK + kk * 32 + lg * 8];
                accO[dt] = __builtin_amdgcn_mfma_f32_16x16x32_bf16(pf, vf, accO[dt], 0, 0, 0);
            }
        }
        __syncthreads();
    }

    #pragma unroll
    for (int r2 = 0; r2 < 4; ++r2) {
        float inv = 1.f / l_run[r2];
        int qi = q0 + w * 16 + lg * 4 + r2;
        #pragma unroll
        for (int dt = 0; dt < 4; ++dt)
            o[(size_t)(b * LL + qi) * DD + hh * DH + dt * 16 + l15] = f2bf(accO[dt][r2] * inv);
    }
}

// ------ embed epilogue: h += e + mask?0:gain*LN(cpe_pre) ------
__global__ __launch_bounds__(256) void embed_ep_kernel(
    const float* __restrict__ cpe_pre, const float* __restrict__ e,
    const int* __restrict__ lengths,
    const float* __restrict__ cpe_g, const float* __restrict__ cpe_lb,
    const float* __restrict__ gain_p, float* __restrict__ h)
{
    int row = blockIdx.x;
    int b = row >> 10, l = row & 1023;
    int t = threadIdx.x;
    __shared__ float red[16];
    const float* cp = cpe_pre + (size_t)row * DD;
    float v0 = cp[t], v1 = cp[t + 256];
    float s = v0 + v1, ss = v0 * v0 + v1 * v1;
    float rs = wave_reduce_sum(s), rss = wave_reduce_sum(ss);
    int lane = t & 63, w = t >> 6;
    if (lane == 0) { red[w] = rs; red[8 + w] = rss; }
    __syncthreads();
    float mean = 0.f, msq = 0.f;
    #pragma unroll
    for (int i = 0; i < 4; ++i) { mean += red[i]; msq += red[8 + i]; }
    mean *= (1.0f / DD); msq *= (1.0f / DD);
    float rstd = rsqrtf(msq - mean * mean + 1e-5f);
    bool maskp = (l >= lengths[b]);
    float gain = *gain_p;
    float pe0 = maskp ? 0.f : gain * ((v0 - mean) * rstd * cpe_g[t] + cpe_lb[t]);
    float pe1 = maskp ? 0.f : gain * ((v1 - mean) * rstd * cpe_g[t + 256] + cpe_lb[t + 256]);
    h[(size_t)row * DD + t]       += e[(size_t)b * DD + t] + pe0;
    h[(size_t)row * DD + t + 256] += e[(size_t)b * DD + t + 256] + pe1;
}

// ---------------- LayerNorm f32 out (final) ----------------
__global__ __launch_bounds__(256) void ln_kernel(
    const float* __restrict__ in, float* __restrict__ out,
    const float* __restrict__ g, const float* __restrict__ bta)
{
    int row = blockIdx.x; int t = threadIdx.x;
    __shared__ float red[16];
    const float* xr = in + (size_t)row * DD;
    float2 v = ((const float2*)xr)[t];
    float s = v.x + v.y, ss = v.x * v.x + v.y * v.y;
    float rs = wave_reduce_sum(s), rss = wave_reduce_sum(ss);
    int lane = t & 63, w = t >> 6;
    if (lane == 0) { red[w] = rs; red[8 + w] = rss; }
    __syncthreads();
    float mean = 0.f, msq = 0.f;
    #pragma unroll
    for (int i = 0; i < 4; ++i) { mean += red[i]; msq += red[8 + i]; }
    mean *= (1.0f / DD); msq *= (1.0f / DD);
    float rstd = rsqrtf(msq - mean * mean + 1e-5f);
    float2 gg = ((const float2*)g)[t], bb = ((const float2*)bta)[t];
    float2 o;
    o.x = (v.x - mean) * rstd * gg.x + bb.x;
    o.y = (v.y - mean) * rstd * gg.y + bb.y;
    ((float2*)(out + (size_t)row * DD))[t] = o;
}

// ---------------- LayerNorm bf16 out ----------------
__global__ __launch_bounds__(256) void ln_bf16_kernel(
    const float* __restrict__ in, unsigned short* __restrict__ out,
    const float* __restrict__ g, const float* __restrict__ bta)
{
    int row = blockIdx.x; int t = threadIdx.x;
    __shared__ float red[16];
    const float* xr = in + (size_t)row * DD;
    float2 v = ((const float2*)xr)[t];
    float s = v.x + v.y, ss = v.x * v.x + v.y * v.y;
    float rs = wave_reduce_sum(s), rss = wave_reduce_sum(ss);
    int lane = t & 63, w = t >> 6;
    if (lane == 0) { red[w] = rs; red[8 + w] = rss; }
    __syncthreads();
    float mean = 0.f, msq = 0.f;
    #pragma unroll
    for (int i = 0; i < 4; ++i) { mean += red[i]; msq += red[8 + i]; }
    mean *= (1.0f / DD); msq *= (1.0f / DD);
    float rstd = rsqrtf(msq - mean * mean + 1e-5f);
    float2 gg = ((const float2*)g)[t], bb = ((const float2*)bta)[t];
    ushort2 o;
    o.x = f2bf((v.x - mean) * rstd * gg.x + bb.x);
    o.y = f2bf((v.y - mean) * rstd * gg.y + bb.y);
    ((ushort2*)(out + (size_t)row * DD))[t] = o;
}

extern "C" void kernel_launch(void* const* d_in, const int* in_sizes, int n_in,
                              void* d_out, int out_size, void* d_ws, size_t ws_size,
                              hipStream_t stream)
{
    const float* x          = (const float*)d_in[0];
    const int*   lengths    = (const int*)  d_in[1];
    const float* input_delay= (const float*)d_in[2];
    const float* c_local    = (const float*)d_in[3];
    const float* c_sink     = (const float*)d_in[4];
    const float* in_w       = (const float*)d_in[5];
    const float* in_b       = (const float*)d_in[6];
    const float* de_w1      = (const float*)d_in[7];
    const float* de_b1      = (const float*)d_in[8];
    const float* de_w2      = (const float*)d_in[9];
    const float* de_b2      = (const float*)d_in[10];
    const float* de_ln_g    = (const float*)d_in[11];
    const float* de_ln_b    = (const float*)d_in[12];
    const float* cpe_w      = (const float*)d_in[13];
    const float* cpe_b      = (const float*)d_in[14];
    const float* cpe_ln_g   = (const float*)d_in[15];
    const float* cpe_ln_b   = (const float*)d_in[16];
    const float* gain       = (const float*)d_in[17];
    const float* alpha      = (const float*)d_in[18];
    const float* beta       = (const float*)d_in[19];
    const float* floorp     = (const float*)d_in[20];
    const float* gammap     = (const float*)d_in[21];
    const float* inproj_w   = (const float*)d_in[22];
    const float* inproj_b   = (const float*)d_in[23];
    const float* outproj_w  = (const float*)d_in[24];
    const float* outproj_b  = (const float*)d_in[25];
    const float* ln1_g      = (const float*)d_in[26];
    const float* ln1_b      = (const float*)d_in[27];
    const float* ln2_g      = (const float*)d_in[28];
    const float* ln2_b      = (const float*)d_in[29];
    const float* ff_w1      = (const float*)d_in[30];
    const float* ff_b1      = (const float*)d_in[31];
    const float* ff_w2      = (const float*)d_in[32];
    const float* ff_b2      = (const float*)d_in[33];
    const float* out_ln_g   = (const float*)d_in[34];
    const float* out_ln_b   = (const float*)d_in[35];

    char* base = (char*)d_ws;
    float* h            = (float*)base;                               // 8 MB
    unsigned short* act1 = (unsigned short*)(base + 8u*1024*1024);    // 4 MB
    char* bigb          = base + 12u*1024*1024;                       // 16 MB shared region
    unsigned short* qkvb = (unsigned short*)bigb;                     // 12 MB (attn phase)
    unsigned short* vtb  = (unsigned short*)(bigb + 12u*1024*1024);   // 4 MB  (attn phase)
    unsigned short* ffb  = (unsigned short*)bigb;                     // 16 MB (FF phase)
    unsigned short* Zb   = (unsigned short*)bigb;                     // 4.46 MB (embed phase)
    unsigned short* x_bf = (unsigned short*)(bigb + 5u*1024*1024);    // 0.5 MB
    float* cpe_pre       = (float*)(bigb + 8u*1024*1024);             // 8 MB
    unsigned short* w_inproj  = (unsigned short*)(base + 28u*1024*1024);
    unsigned short* w_outproj = w_inproj  + (size_t)3*1536*512;
    unsigned short* w_ff1     = w_outproj + (size_t)3*512*512;
    unsigned short* w_ff2     = w_ff1     + (size_t)3*2048*512;
    unsigned short* w_in      = w_ff2     + (size_t)3*512*2048;
    unsigned short* w_cpe     = w_in      + (size_t)512*64;
    float* e                  = (float*)(w_cpe + (size_t)512*544);

    // weight / input conversions (every launch; deterministic)
    cvt_kernel<<<128, 256, 0, stream>>>(x, x_bf, MM * DIN);
    cvt_kernel<<<2048, 256, 0, stream>>>(inproj_w, w_inproj, 3 * 1536 * 512);
    cvt_kernel<<<1024, 256, 0, stream>>>(outproj_w, w_outproj, 3 * 512 * 512);
    cvt_kernel<<<2048, 256, 0, stream>>>(ff_w1, w_ff1, 3 * 2048 * 512);
    cvt_kernel<<<2048, 256, 0, stream>>>(ff_w2, w_ff2, 3 * 512 * 2048);
    cvt_kernel<<<64, 256, 0, stream>>>(in_w, w_in, 512 * 64);
    cpe_pad_kernel<<<1024, 256, 0, stream>>>(cpe_w, w_cpe);

    delay_kernel<<<BB, 512, 0, stream>>>(input_delay, de_w1, de_b1, de_w2, de_b2, de_ln_g, de_ln_b, e);
    build_z_kernel<<<MM, 256, 0, stream>>>(c_local, c_sink, Zb);

    // h0 = x @ in_w^T + in_b
    mfma_gemm<<<dim3(DD / 128, MM / 128), 256, 0, stream>>>(
        x_bf, w_in, in_b, nullptr, h, nullptr, MM, DD, DIN, 0);
    // cpe_pre = Z @ cpe_w^T + cpe_b
    mfma_gemm<<<dim3(DD / 128, MM / 128), 256, 0, stream>>>(
        Zb, w_cpe, cpe_b, nullptr, cpe_pre, nullptr, MM, DD, FEATP, 0);
    embed_ep_kernel<<<MM, 256, 0, stream>>>(cpe_pre, e, lengths, cpe_ln_g, cpe_ln_b, gain, h);

    for (int i = 0; i < NLAYER; ++i) {
        ln_bf16_kernel<<<MM, 256, 0, stream>>>(h, act1, ln1_g + (size_t)i * DD, ln1_b + (size_t)i * DD);
        mfma_gemm<<<dim3(1536 / 128, MM / 128), 256, 0, stream>>>(
            act1, w_inproj + (size_t)i * 1536 * 512, inproj_b + (size_t)i * 1536,
            nullptr, nullptr, qkvb, MM, 1536, DD, 1);
        vtrans_kernel<<<dim3(LL / 64, HH, BB), 256, 0, stream>>>(qkvb, vtb);
        attn_mfma<<<dim3(LL / 64, HH, BB), 256, 0, stream>>>(qkvb, vtb, c_local, c_sink, lengths,
                                                             alpha, beta, floorp, gammap, act1);
        mfma_gemm<<<dim3(DD / 128, MM / 128), 256, 0, stream>>>(
            act1, w_outproj + (size_t)i * 512 * 512, outproj_b + (size_t)i * DD,
            h, h, nullptr, MM, DD, DD, 2);
        ln_bf16_kernel<<<MM, 256, 0, stream>>>(h, act1, ln2_g + (size_t)i * DD, ln2_b + (size_t)i * DD);
        mfma_gemm<<<dim3(DFF / 128, MM / 128), 256, 0, stream>>>(
            act1, w_ff1 + (size_t)i * 2048 * 512, ff_b1 + (size_t)i * DFF,
            nullptr, nullptr, ffb, MM, DFF, DD, 3);
        mfma_gemm<<<dim3(DD / 128, MM / 128), 256, 0, stream>>>(
            ffb, w_ff2 + (size_t)i * 512 * 2048, ff_b2 + (size_t)i * DD,
            h, h, nullptr, MM, DD, DFF, 2);
    }
    ln_kernel<<<MM, 256, 0, stream>>>(h, (float*)d_out, out_ln_g, out_ln_b);
}

// Round 5
// 734.931 us; speedup vs baseline: 8.2280x; 1.0352x over previous
//
#include <hip/hip_runtime.h>
#include <math.h>

#define BB 4
#define LL 1024
#define DIN 64
#define DD 512
#define HH 8
#define DH 64
#define NLAYER 3
#define DFF 2048
#define FEAT 530
#define FEATP 544
#define MM 4096

typedef float f32x4 __attribute__((ext_vector_type(4)));
typedef short s16x8 __attribute__((ext_vector_type(8)));

__device__ __forceinline__ unsigned short f2bf(float f) {
    unsigned int u = __float_as_uint(f);
    u += 0x7fffu + ((u >> 16) & 1u);
    return (unsigned short)(u >> 16);
}
__device__ __forceinline__ float gelu_exact(float x) {
    return 0.5f * x * (1.0f + erff(x * 0.7071067811865475f));
}
__device__ __forceinline__ float wave_reduce_sum(float v) {
    #pragma unroll
    for (int o = 32; o; o >>= 1) v += __shfl_down(v, o);
    return v;
}
__device__ __forceinline__ void gload16(const unsigned short* g, unsigned short* l) {
    __builtin_amdgcn_global_load_lds(
        (const __attribute__((address_space(1))) unsigned int*)g,
        (__attribute__((address_space(3))) unsigned int*)l, 16, 0, 0);
}

// ---------------- generic f32 -> bf16 convert ----------------
__global__ __launch_bounds__(256) void cvt_kernel(
    const float* __restrict__ in, unsigned short* __restrict__ out, int n)
{
    for (int i = blockIdx.x * 256 + threadIdx.x; i < n; i += gridDim.x * 256)
        out[i] = f2bf(in[i]);
}

// ---------------- cpe_w [512][530] f32 -> [512][544] bf16 (zero pad) ----------------
__global__ __launch_bounds__(256) void cpe_pad_kernel(
    const float* __restrict__ in, unsigned short* __restrict__ out)
{
    for (int i = blockIdx.x * 256 + threadIdx.x; i < DD * FEATP; i += gridDim.x * 256) {
        int r = i / FEATP, c = i - r * FEATP;
        out[i] = (c < FEAT) ? f2bf(in[(size_t)r * FEAT + c]) : 0;
    }
}

// ---------------- build Z[M][544] bf16: PE + raw + RBFs ----------------
__global__ __launch_bounds__(256) void build_z_kernel(
    const float* __restrict__ c_local, const float* __restrict__ c_sink,
    unsigned short* __restrict__ Z)
{
    int row = blockIdx.x;
    int b = row >> 10, l = row & 1023;
    int t = threadIdx.x;
    unsigned short* zr = Z + (size_t)row * FEATP;
    for (int d = t; d < DD; d += 256) {
        int i = d >> 1;
        float dv = expf((float)(2 * i) * (-0.017988946135618352f)); // -ln(1e4)/512
        float ang = (float)l * dv;
        zr[d] = f2bf((d & 1) ? cosf(ang) : sinf(ang));
    }
    if (t < 32) {
        float cl = c_local[(size_t)b * LL + l]; cl = fminf(fmaxf(cl, 0.f), 1.f);
        float cs = c_sink [(size_t)b * LL + l]; cs = fminf(fmaxf(cs, 0.f), 1.f);
        float v = 0.f;
        if (t == 0) v = cl;
        else if (t == 1) v = cs;
        else if (t < 10)  { float c = (float)(t - 2) * (1.0f / 7.0f);  float df = (cl - c) / 0.200001f; v = expf(-0.5f * df * df); }
        else if (t < 18)  { float c = (float)(t - 10) * (1.0f / 7.0f); float df = (cs - c) / 0.200001f; v = expf(-0.5f * df * df); }
        zr[512 + t] = (t < 18) ? f2bf(v) : 0;
    }
}

// ---------------- sink row: srow[b][k] = beta*(floor+(1-floor)*(cs^gamma)), 0 if masked ----------------
__global__ __launch_bounds__(256) void sink_kernel(
    const float* __restrict__ c_sink, const int* __restrict__ lengths,
    const float* __restrict__ beta_p, const float* __restrict__ floor_p,
    const float* __restrict__ gamma_p, float* __restrict__ srow)
{
    int i = blockIdx.x * 256 + threadIdx.x;
    int b = i >> 10, k = i & 1023;
    float beta = *beta_p, flr = *floor_p, gmm = *gamma_p;
    float cs = c_sink[i]; cs = fminf(fmaxf(cs, 0.f), 1.f);
    float v = beta * (flr + (1.f - flr) * powf(cs + 1e-6f, gmm));
    srow[i] = (k < lengths[b]) ? v : 0.f;
}

// ---------------- delay feature encoder: e[B,D] ----------------
__global__ __launch_bounds__(512) void delay_kernel(
    const float* __restrict__ delay, const float* __restrict__ w1, const float* __restrict__ b1,
    const float* __restrict__ w2, const float* __restrict__ b2,
    const float* __restrict__ lng, const float* __restrict__ lnb,
    float* __restrict__ e)
{
    int b = blockIdx.x;
    int t = threadIdx.x;
    __shared__ float g1[DD];
    __shared__ float red[16];
    float t1 = delay[b] * w1[t] + b1[t];
    g1[t] = gelu_exact(t1);
    __syncthreads();
    const float* wr = w2 + (size_t)t * DD;
    float s = b2[t];
    for (int j = 0; j < DD; j += 4) {
        float4 w4 = *(const float4*)(wr + j);
        s += w4.x * g1[j] + w4.y * g1[j+1] + w4.z * g1[j+2] + w4.w * g1[j+3];
    }
    float rs = wave_reduce_sum(s);
    float rss = wave_reduce_sum(s * s);
    int lane = t & 63, w = t >> 6;
    if (lane == 0) { red[w] = rs; red[8 + w] = rss; }
    __syncthreads();
    float mean = 0.f, msq = 0.f;
    #pragma unroll
    for (int i = 0; i < 8; ++i) { mean += red[i]; msq += red[8 + i]; }
    mean *= (1.0f / DD); msq *= (1.0f / DD);
    float rstd = rsqrtf(msq - mean * mean + 1e-5f);
    e[(size_t)b * DD + t] = (s - mean) * rstd * lng[t] + lnb[t];
}

// ---- MFMA GEMM: out[M,N] = epilogue(A[M,K]bf16 @ W[N,K]^T bf16 + bias) ----
// global_load_lds staging, linear [128][32] LDS + XOR chunk swizzle both sides.
// mode 0: f32 out = acc+bias ; 1: bf16 out = acc+bias ;
// mode 2: f32 out = acc+bias+resid ; 3: bf16 out = gelu(acc+bias)
__global__ __launch_bounds__(256) void mfma_gemm(
    const unsigned short* __restrict__ A, const unsigned short* __restrict__ W,
    const float* __restrict__ bias, const float* __restrict__ resid,
    float* __restrict__ outf, unsigned short* __restrict__ outb,
    int M, int N, int K, int mode)
{
    __shared__ __align__(16) unsigned short As[128 * 32];
    __shared__ __align__(16) unsigned short Ws[128 * 32];
    int bm = blockIdx.y * 128, bn = blockIdx.x * 128;
    int t = threadIdx.x;
    int lane = t & 63, wid = t >> 6;
    int wr = wid >> 1, wc = wid & 1;
    int l15 = lane & 15, lg = lane >> 4;

    // staging: wave `wid` stages rows [wid*32, wid*32+32) via 2 instrs of 16 rows.
    // lane l covers row srow0+i*16, physical chunk (l&3); source chunk XOR-preswizzled.
    int srow0 = wid * 32 + (lane >> 2);
    int sc8 = ((lane & 3) ^ ((lane >> 2) & 3) ^ ((lane >> 4) & 3)) * 8;  // shorts
    // fragment read: logical chunk lg of row -> physical lg ^ (row&3) ^ ((row>>2)&3)
    int chunk8 = (lg ^ (l15 & 3) ^ ((l15 >> 2) & 3)) * 8;

    f32x4 acc[4][4] = {};
    int nk = K >> 5;

    for (int ks = 0; ks < nk; ++ks) {
        int kb = ks * 32;
        #pragma unroll
        for (int i = 0; i < 2; ++i) {
            int row = srow0 + i * 16;
            gload16(A + (size_t)(bm + row) * K + kb + sc8, &As[(wid * 2 + i) * 512]);
            gload16(W + (size_t)(bn + row) * K + kb + sc8, &Ws[(wid * 2 + i) * 512]);
        }
        __syncthreads();
        s16x8 af[4], wf[4];
        #pragma unroll
        for (int mi = 0; mi < 4; ++mi)
            af[mi] = *(const s16x8*)&As[(wr * 64 + mi * 16 + l15) * 32 + chunk8];
        #pragma unroll
        for (int ni = 0; ni < 4; ++ni)
            wf[ni] = *(const s16x8*)&Ws[(wc * 64 + ni * 16 + l15) * 32 + chunk8];
        #pragma unroll
        for (int mi = 0; mi < 4; ++mi)
            #pragma unroll
            for (int ni = 0; ni < 4; ++ni)
                acc[mi][ni] = __builtin_amdgcn_mfma_f32_16x16x32_bf16(af[mi], wf[ni], acc[mi][ni], 0, 0, 0);
        __syncthreads();
    }

    int rbase = (lane >> 4) * 4;
    #pragma unroll
    for (int mi = 0; mi < 4; ++mi) {
        #pragma unroll
        for (int ni = 0; ni < 4; ++ni) {
            int n = bn + wc * 64 + ni * 16 + l15;
            float bz = bias[n];
            #pragma unroll
            for (int r2 = 0; r2 < 4; ++r2) {
                int m = bm + wr * 64 + mi * 16 + rbase + r2;
                float v = acc[mi][ni][r2] + bz;
                size_t o = (size_t)m * N + n;
                if (mode == 0)      outf[o] = v;
                else if (mode == 1) outb[o] = f2bf(v);
                else if (mode == 2) outf[o] = v + resid[o];
                else                outb[o] = f2bf(gelu_exact(v));
            }
        }
    }
}

// ---- V transpose: qkv V part -> Vt[b][h][d][l] ----
__global__ __launch_bounds__(256) void vtrans_kernel(
    const unsigned short* __restrict__ qkv, unsigned short* __restrict__ Vt)
{
    __shared__ unsigned short Ts[64 * 68];
    int l0 = blockIdx.x * 64;
    int hh = blockIdx.y;
    int b  = blockIdx.z;
    int t  = threadIdx.x;
    #pragma unroll
    for (int u = 0; u < 2; ++u) {
        int idx = t + u * 256;
        int r = idx >> 3, c8 = idx & 7;
        uint4 v = *(const uint4*)(qkv + (size_t)(b * LL + l0 + r) * 1536 + 1024 + hh * DH + c8 * 8);
        *(uint4*)&Ts[r * 68 + c8 * 8] = v;
    }
    __syncthreads();
    #pragma unroll
    for (int u = 0; u < 2; ++u) {
        int d = (t >> 3) + u * 32;
        int c = t & 7;
        unsigned short tmp[8];
        #pragma unroll
        for (int j = 0; j < 8; ++j) tmp[j] = Ts[(c * 8 + j) * 68 + d];
        *(uint4*)(Vt + ((size_t)((b * HH + hh) * DH + d)) * LL + l0 + c * 8) = *(const uint4*)tmp;
    }
}

// ------------- MFMA flash attention: block = (b, h, 64-q tile), 4 waves -------------
#define SK 72
#define SPB 72
__global__ __launch_bounds__(256) void attn_mfma(
    const unsigned short* __restrict__ qkv, const unsigned short* __restrict__ Vt,
    const float* __restrict__ c_local, const float* __restrict__ srow,
    const int* __restrict__ lengths,
    const float* __restrict__ alpha_p,
    unsigned short* __restrict__ o)
{
    __shared__ __align__(16) unsigned short Ks[64 * SK];
    __shared__ __align__(16) unsigned short Vts[64 * SK];
    __shared__ __align__(16) unsigned short Psb[64 * SPB];

    int q0 = blockIdx.x * 64;
    int hh = blockIdx.y;
    int b  = blockIdx.z;
    int t  = threadIdx.x;
    int lane = t & 63, w = t >> 6;
    int l15 = lane & 15, lg = lane >> 4;
    int len = lengths[b];
    const float alpha = *alpha_p;

    // Q fragments (2 k-steps), rows = q0 + w*16 + l15
    const unsigned short* qrow = qkv + (size_t)(b * LL + q0 + w * 16 + l15) * 1536 + hh * DH;
    s16x8 qf0 = *(const s16x8*)(qrow + lg * 8);
    s16x8 qf1 = *(const s16x8*)(qrow + 32 + lg * 8);

    // per-row neighbor bias (rows q0 + w*16 + lg*4 + r2)
    float cm1[4], cp1[4];
    #pragma unroll
    for (int r2 = 0; r2 < 4; ++r2) {
        int qi = q0 + w * 16 + lg * 4 + r2;
        cm1[r2] = 0.f; cp1[r2] = 0.f;
        if (qi >= 1 && qi < len) {
            int src = (qi == 1 || qi == LL - 1) ? qi : qi - 1;
            cm1[r2] = alpha * c_local[(size_t)b * LL + src];
        }
        if (qi + 1 < LL && qi < len)
            cp1[r2] = alpha * c_local[(size_t)b * LL + qi + 1];
    }
    // sink applies only to q-row 0 (r2==0 of this group)
    bool need_sink = (q0 == 0 && w == 0 && lg == 0);

    float m_run[4], l_run[4];
    f32x4 accO[4] = {};
    #pragma unroll
    for (int r2 = 0; r2 < 4; ++r2) { m_run[r2] = -1e30f; l_run[r2] = 0.f; }

    int sr = t >> 3, sc8 = (t & 7) * 8;
    const unsigned short* kbase = qkv + (size_t)(b * LL) * 1536 + 512 + hh * DH;
    const unsigned short* vbase = Vt + ((size_t)((b * HH + hh) * DH)) * LL;

    uint4 pk0 = *(const uint4*)(kbase + (size_t)sr * 1536 + sc8);
    uint4 pk1 = *(const uint4*)(kbase + (size_t)(sr + 32) * 1536 + sc8);
    uint4 pv0 = *(const uint4*)(vbase + (size_t)sr * LL + sc8);
    uint4 pv1 = *(const uint4*)(vbase + (size_t)(sr + 32) * LL + sc8);

    for (int k0 = 0; k0 < LL; k0 += 64) {
        *(uint4*)&Ks[sr * SK + sc8]         = pk0;
        *(uint4*)&Ks[(sr + 32) * SK + sc8]  = pk1;
        *(uint4*)&Vts[sr * SK + sc8]        = pv0;
        *(uint4*)&Vts[(sr + 32) * SK + sc8] = pv1;
        if (k0 + 64 < LL) {
            pk0 = *(const uint4*)(kbase + (size_t)(k0 + 64 + sr) * 1536 + sc8);
            pk1 = *(const uint4*)(kbase + (size_t)(k0 + 64 + sr + 32) * 1536 + sc8);
            pv0 = *(const uint4*)(vbase + (size_t)sr * LL + k0 + 64 + sc8);
            pv1 = *(const uint4*)(vbase + (size_t)(sr + 32) * LL + k0 + 64 + sc8);
        }
        __syncthreads();

        // S = Q K^T
        f32x4 accS[4] = {};
        #pragma unroll
        for (int ct = 0; ct < 4; ++ct) {
            s16x8 kf0 = *(const s16x8*)&Ks[(ct * 16 + l15) * SK + lg * 8];
            s16x8 kf1 = *(const s16x8*)&Ks[(ct * 16 + l15) * SK + 32 + lg * 8];
            accS[ct] = __builtin_amdgcn_mfma_f32_16x16x32_bf16(qf0, kf0, accS[ct], 0, 0, 0);
            accS[ct] = __builtin_amdgcn_mfma_f32_16x16x32_bf16(qf1, kf1, accS[ct], 0, 0, 0);
        }

        // bias + mask, row stats, online update, P -> LDS (bf16)
        float m4[4] = { -1e30f, -1e30f, -1e30f, -1e30f };
        #pragma unroll
        for (int ct = 0; ct < 4; ++ct) {
            int k = k0 + ct * 16 + l15;
            bool maskk = (k >= len);
            float sink_ct = need_sink ? srow[(size_t)b * LL + k] : 0.f;
            #pragma unroll
            for (int r2 = 0; r2 < 4; ++r2) {
                int qi = q0 + w * 16 + lg * 4 + r2;
                float v = accS[ct][r2] * 0.125f;
                if (k == qi - 1) v += cm1[r2];
                else if (k == qi + 1 && !maskk) v += cp1[r2];
                if (r2 == 0) v += sink_ct;   // nonzero only for q-row 0 lanes
                if (maskk) v -= 10000.f;
                accS[ct][r2] = v;
                m4[r2] = fmaxf(m4[r2], v);
            }
        }
        #pragma unroll
        for (int r2 = 0; r2 < 4; ++r2) {
            #pragma unroll
            for (int msk = 1; msk < 16; msk <<= 1) m4[r2] = fmaxf(m4[r2], __shfl_xor(m4[r2], msk));
            float mnew = fmaxf(m_run[r2], m4[r2]);
            float scl = __expf(m_run[r2] - mnew);
            m_run[r2] = mnew;
            float rowsum = 0.f;
            #pragma unroll
            for (int ct = 0; ct < 4; ++ct) {
                float p = __expf(accS[ct][r2] - mnew);
                rowsum += p;
                Psb[(w * 16 + lg * 4 + r2) * SPB + ct * 16 + l15] = f2bf(p);
            }
            #pragma unroll
            for (int msk = 1; msk < 16; msk <<= 1) rowsum += __shfl_xor(rowsum, msk);
            l_run[r2] = l_run[r2] * scl + rowsum;
            #pragma unroll
            for (int dt = 0; dt < 4; ++dt) accO[dt][r2] *= scl;
        }

        // O += P @ V (wave-local P rows; bf16 fragments straight from LDS)
        #pragma unroll
        for (int kk = 0; kk < 2; ++kk) {
            s16x8 pf = *(const s16x8*)&Psb[(w * 16 + l15) * SPB + kk * 32 + lg * 8];
            #pragma unroll
            for (int dt = 0; dt < 4; ++dt) {
                s16x8 vf = *(const s16x8*)&Vts[(dt * 16 + l15) * SK + kk * 32 + lg * 8];
                accO[dt] = __builtin_amdgcn_mfma_f32_16x16x32_bf16(pf, vf, accO[dt], 0, 0, 0);
            }
        }
        __syncthreads();
    }

    #pragma unroll
    for (int r2 = 0; r2 < 4; ++r2) {
        float inv = 1.f / l_run[r2];
        int qi = q0 + w * 16 + lg * 4 + r2;
        #pragma unroll
        for (int dt = 0; dt < 4; ++dt)
            o[(size_t)(b * LL + qi) * DD + hh * DH + dt * 16 + l15] = f2bf(accO[dt][r2] * inv);
    }
}

// ------ embed epilogue: h += e + mask?0:gain*LN(cpe_pre) ------
__global__ __launch_bounds__(256) void embed_ep_kernel(
    const float* __restrict__ cpe_pre, const float* __restrict__ e,
    const int* __restrict__ lengths,
    const float* __restrict__ cpe_g, const float* __restrict__ cpe_lb,
    const float* __restrict__ gain_p, float* __restrict__ h)
{
    int row = blockIdx.x;
    int b = row >> 10, l = row & 1023;
    int t = threadIdx.x;
    __shared__ float red[16];
    const float* cp = cpe_pre + (size_t)row * DD;
    float v0 = cp[t], v1 = cp[t + 256];
    float s = v0 + v1, ss = v0 * v0 + v1 * v1;
    float rs = wave_reduce_sum(s), rss = wave_reduce_sum(ss);
    int lane = t & 63, w = t >> 6;
    if (lane == 0) { red[w] = rs; red[8 + w] = rss; }
    __syncthreads();
    float mean = 0.f, msq = 0.f;
    #pragma unroll
    for (int i = 0; i < 4; ++i) { mean += red[i]; msq += red[8 + i]; }
    mean *= (1.0f / DD); msq *= (1.0f / DD);
    float rstd = rsqrtf(msq - mean * mean + 1e-5f);
    bool maskp = (l >= lengths[b]);
    float gain = *gain_p;
    float pe0 = maskp ? 0.f : gain * ((v0 - mean) * rstd * cpe_g[t] + cpe_lb[t]);
    float pe1 = maskp ? 0.f : gain * ((v1 - mean) * rstd * cpe_g[t + 256] + cpe_lb[t + 256]);
    h[(size_t)row * DD + t]       += e[(size_t)b * DD + t] + pe0;
    h[(size_t)row * DD + t + 256] += e[(size_t)b * DD + t + 256] + pe1;
}

// ---------------- LayerNorm f32 out (final) ----------------
__global__ __launch_bounds__(256) void ln_kernel(
    const float* __restrict__ in, float* __restrict__ out,
    const float* __restrict__ g, const float* __restrict__ bta)
{
    int row = blockIdx.x; int t = threadIdx.x;
    __shared__ float red[16];
    const float* xr = in + (size_t)row * DD;
    float2 v = ((const float2*)xr)[t];
    float s = v.x + v.y, ss = v.x * v.x + v.y * v.y;
    float rs = wave_reduce_sum(s), rss = wave_reduce_sum(ss);
    int lane = t & 63, w = t >> 6;
    if (lane == 0) { red[w] = rs; red[8 + w] = rss; }
    __syncthreads();
    float mean = 0.f, msq = 0.f;
    #pragma unroll
    for (int i = 0; i < 4; ++i) { mean += red[i]; msq += red[8 + i]; }
    mean *= (1.0f / DD); msq *= (1.0f / DD);
    float rstd = rsqrtf(msq - mean * mean + 1e-5f);
    float2 gg = ((const float2*)g)[t], bb = ((const float2*)bta)[t];
    float2 o;
    o.x = (v.x - mean) * rstd * gg.x + bb.x;
    o.y = (v.y - mean) * rstd * gg.y + bb.y;
    ((float2*)(out + (size_t)row * DD))[t] = o;
}

// ---------------- LayerNorm bf16 out ----------------
__global__ __launch_bounds__(256) void ln_bf16_kernel(
    const float* __restrict__ in, unsigned short* __restrict__ out,
    const float* __restrict__ g, const float* __restrict__ bta)
{
    int row = blockIdx.x; int t = threadIdx.x;
    __shared__ float red[16];
    const float* xr = in + (size_t)row * DD;
    float2 v = ((const float2*)xr)[t];
    float s = v.x + v.y, ss = v.x * v.x + v.y * v.y;
    float rs = wave_reduce_sum(s), rss = wave_reduce_sum(ss);
    int lane = t & 63, w = t >> 6;
    if (lane == 0) { red[w] = rs; red[8 + w] = rss; }
    __syncthreads();
    float mean = 0.f, msq = 0.f;
    #pragma unroll
    for (int i = 0; i < 4; ++i) { mean += red[i]; msq += red[8 + i]; }
    mean *= (1.0f / DD); msq *= (1.0f / DD);
    float rstd = rsqrtf(msq - mean * mean + 1e-5f);
    float2 gg = ((const float2*)g)[t], bb = ((const float2*)bta)[t];
    ushort2 o;
    o.x = f2bf((v.x - mean) * rstd * gg.x + bb.x);
    o.y = f2bf((v.y - mean) * rstd * gg.y + bb.y);
    ((ushort2*)(out + (size_t)row * DD))[t] = o;
}

extern "C" void kernel_launch(void* const* d_in, const int* in_sizes, int n_in,
                              void* d_out, int out_size, void* d_ws, size_t ws_size,
                              hipStream_t stream)
{
    const float* x          = (const float*)d_in[0];
    const int*   lengths    = (const int*)  d_in[1];
    const float* input_delay= (const float*)d_in[2];
    const float* c_local    = (const float*)d_in[3];
    const float* c_sink     = (const float*)d_in[4];
    const float* in_w       = (const float*)d_in[5];
    const float* in_b       = (const float*)d_in[6];
    const float* de_w1      = (const float*)d_in[7];
    const float* de_b1      = (const float*)d_in[8];
    const float* de_w2      = (const float*)d_in[9];
    const float* de_b2      = (const float*)d_in[10];
    const float* de_ln_g    = (const float*)d_in[11];
    const float* de_ln_b    = (const float*)d_in[12];
    const float* cpe_w      = (const float*)d_in[13];
    const float* cpe_b      = (const float*)d_in[14];
    const float* cpe_ln_g   = (const float*)d_in[15];
    const float* cpe_ln_b   = (const float*)d_in[16];
    const float* gain       = (const float*)d_in[17];
    const float* alpha      = (const float*)d_in[18];
    const float* beta       = (const float*)d_in[19];
    const float* floorp     = (const float*)d_in[20];
    const float* gammap     = (const float*)d_in[21];
    const float* inproj_w   = (const float*)d_in[22];
    const float* inproj_b   = (const float*)d_in[23];
    const float* outproj_w  = (const float*)d_in[24];
    const float* outproj_b  = (const float*)d_in[25];
    const float* ln1_g      = (const float*)d_in[26];
    const float* ln1_b      = (const float*)d_in[27];
    const float* ln2_g      = (const float*)d_in[28];
    const float* ln2_b      = (const float*)d_in[29];
    const float* ff_w1      = (const float*)d_in[30];
    const float* ff_b1      = (const float*)d_in[31];
    const float* ff_w2      = (const float*)d_in[32];
    const float* ff_b2      = (const float*)d_in[33];
    const float* out_ln_g   = (const float*)d_in[34];
    const float* out_ln_b   = (const float*)d_in[35];

    char* base = (char*)d_ws;
    float* h            = (float*)base;                               // 8 MB
    unsigned short* act1 = (unsigned short*)(base + 8u*1024*1024);    // 4 MB
    char* bigb          = base + 12u*1024*1024;                       // 16 MB shared region
    unsigned short* qkvb = (unsigned short*)bigb;                     // 12 MB (attn phase)
    unsigned short* vtb  = (unsigned short*)(bigb + 12u*1024*1024);   // 4 MB  (attn phase)
    unsigned short* ffb  = (unsigned short*)bigb;                     // 16 MB (FF phase)
    unsigned short* Zb   = (unsigned short*)bigb;                     // 4.46 MB (embed phase)
    unsigned short* x_bf = (unsigned short*)(bigb + 5u*1024*1024);    // 0.5 MB
    float* cpe_pre       = (float*)(bigb + 8u*1024*1024);             // 8 MB
    unsigned short* w_inproj  = (unsigned short*)(base + 28u*1024*1024);
    unsigned short* w_outproj = w_inproj  + (size_t)3*1536*512;
    unsigned short* w_ff1     = w_outproj + (size_t)3*512*512;
    unsigned short* w_ff2     = w_ff1     + (size_t)3*2048*512;
    unsigned short* w_in      = w_ff2     + (size_t)3*512*2048;
    unsigned short* w_cpe     = w_in      + (size_t)512*64;
    float* e                  = (float*)(w_cpe + (size_t)512*544);
    float* srow               = e + (size_t)BB*DD;

    // weight / input conversions (every launch; deterministic)
    cvt_kernel<<<128, 256, 0, stream>>>(x, x_bf, MM * DIN);
    cvt_kernel<<<2048, 256, 0, stream>>>(inproj_w, w_inproj, 3 * 1536 * 512);
    cvt_kernel<<<1024, 256, 0, stream>>>(outproj_w, w_outproj, 3 * 512 * 512);
    cvt_kernel<<<2048, 256, 0, stream>>>(ff_w1, w_ff1, 3 * 2048 * 512);
    cvt_kernel<<<2048, 256, 0, stream>>>(ff_w2, w_ff2, 3 * 512 * 2048);
    cvt_kernel<<<64, 256, 0, stream>>>(in_w, w_in, 512 * 64);
    cpe_pad_kernel<<<1024, 256, 0, stream>>>(cpe_w, w_cpe);

    delay_kernel<<<BB, 512, 0, stream>>>(input_delay, de_w1, de_b1, de_w2, de_b2, de_ln_g, de_ln_b, e);
    build_z_kernel<<<MM, 256, 0, stream>>>(c_local, c_sink, Zb);
    sink_kernel<<<BB * LL / 256, 256, 0, stream>>>(c_sink, lengths, beta, floorp, gammap, srow);

    // h0 = x @ in_w^T + in_b
    mfma_gemm<<<dim3(DD / 128, MM / 128), 256, 0, stream>>>(
        x_bf, w_in, in_b, nullptr, h, nullptr, MM, DD, DIN, 0);
    // cpe_pre = Z @ cpe_w^T + cpe_b
    mfma_gemm<<<dim3(DD / 128, MM / 128), 256, 0, stream>>>(
        Zb, w_cpe, cpe_b, nullptr, cpe_pre, nullptr, MM, DD, FEATP, 0);
    embed_ep_kernel<<<MM, 256, 0, stream>>>(cpe_pre, e, lengths, cpe_ln_g, cpe_ln_b, gain, h);

    for (int i = 0; i < NLAYER; ++i) {
        ln_bf16_kernel<<<MM, 256, 0, stream>>>(h, act1, ln1_g + (size_t)i * DD, ln1_b + (size_t)i * DD);
        mfma_gemm<<<dim3(1536 / 128, MM / 128), 256, 0, stream>>>(
            act1, w_inproj + (size_t)i * 1536 * 512, inproj_b + (size_t)i * 1536,
            nullptr, nullptr, qkvb, MM, 1536, DD, 1);
        vtrans_kernel<<<dim3(LL / 64, HH, BB), 256, 0, stream>>>(qkvb, vtb);
        attn_mfma<<<dim3(LL / 64, HH, BB), 256, 0, stream>>>(qkvb, vtb, c_local, srow, lengths,
                                                             alpha, act1);
        mfma_gemm<<<dim3(DD / 128, MM / 128), 256, 0, stream>>>(
            act1, w_outproj + (size_t)i * 512 * 512, outproj_b + (size_t)i * DD,
            h, h, nullptr, MM, DD, DD, 2);
        ln_bf16_kernel<<<MM, 256, 0, stream>>>(h, act1, ln2_g + (size_t)i * DD, ln2_b + (size_t)i * DD);
        mfma_gemm<<<dim3(DFF / 128, MM / 128), 256, 0, stream>>>(
            act1, w_ff1 + (size_t)i * 2048 * 512, ff_b1 + (size_t)i * DFF,
            nullptr, nullptr, ffb, MM, DFF, DD, 3);
        mfma_gemm<<<dim3(DD / 128, MM / 128), 256, 0, stream>>>(
            ffb, w_ff2 + (size_t)i * 512 * 2048, ff_b2 + (size_t)i * DD,
            h, h, nullptr, MM, DD, DFF, 2);
    }
    ln_kernel<<<MM, 256, 0, stream>>>(h, (float*)d_out, out_ln_g, out_ln_b);
}

// Round 6
// 521.261 us; speedup vs baseline: 11.6007x; 1.4099x over previous
//
#include <hip/hip_runtime.h>
#include <math.h>

#define BB 4
#define LL 1024
#define DIN 64
#define DD 512
#define HH 8
#define DH 64
#define NLAYER 3
#define DFF 2048
#define FEAT 530
#define FEATP 544
#define MM 4096

typedef float f32x4 __attribute__((ext_vector_type(4)));
typedef short s16x8 __attribute__((ext_vector_type(8)));

__device__ __forceinline__ unsigned short f2bf(float f) {
    unsigned int u = __float_as_uint(f);
    u += 0x7fffu + ((u >> 16) & 1u);
    return (unsigned short)(u >> 16);
}
__device__ __forceinline__ float gelu_exact(float x) {
    return 0.5f * x * (1.0f + erff(x * 0.7071067811865475f));
}
__device__ __forceinline__ float wave_reduce_sum(float v) {
    #pragma unroll
    for (int o = 32; o; o >>= 1) v += __shfl_down(v, o);
    return v;
}
__device__ __forceinline__ void gload16(const unsigned short* g, unsigned short* l) {
    __builtin_amdgcn_global_load_lds(
        (const __attribute__((address_space(1))) unsigned int*)g,
        (__attribute__((address_space(3))) unsigned int*)l, 16, 0, 0);
}

// ---------------- generic f32 -> bf16 convert ----------------
__global__ __launch_bounds__(256) void cvt_kernel(
    const float* __restrict__ in, unsigned short* __restrict__ out, int n)
{
    for (int i = blockIdx.x * 256 + threadIdx.x; i < n; i += gridDim.x * 256)
        out[i] = f2bf(in[i]);
}

// ---------------- cpe_w [512][530] f32 -> [512][544] bf16 (zero pad) ----------------
__global__ __launch_bounds__(256) void cpe_pad_kernel(
    const float* __restrict__ in, unsigned short* __restrict__ out)
{
    for (int i = blockIdx.x * 256 + threadIdx.x; i < DD * FEATP; i += gridDim.x * 256) {
        int r = i / FEATP, c = i - r * FEATP;
        out[i] = (c < FEAT) ? f2bf(in[(size_t)r * FEAT + c]) : 0;
    }
}

// ---------------- build Z[M][544] bf16: PE + raw + RBFs ----------------
__global__ __launch_bounds__(256) void build_z_kernel(
    const float* __restrict__ c_local, const float* __restrict__ c_sink,
    unsigned short* __restrict__ Z)
{
    int row = blockIdx.x;
    int b = row >> 10, l = row & 1023;
    int t = threadIdx.x;
    unsigned short* zr = Z + (size_t)row * FEATP;
    for (int d = t; d < DD; d += 256) {
        int i = d >> 1;
        float dv = expf((float)(2 * i) * (-0.017988946135618352f)); // -ln(1e4)/512
        float ang = (float)l * dv;
        zr[d] = f2bf((d & 1) ? cosf(ang) : sinf(ang));
    }
    if (t < 32) {
        float cl = c_local[(size_t)b * LL + l]; cl = fminf(fmaxf(cl, 0.f), 1.f);
        float cs = c_sink [(size_t)b * LL + l]; cs = fminf(fmaxf(cs, 0.f), 1.f);
        float v = 0.f;
        if (t == 0) v = cl;
        else if (t == 1) v = cs;
        else if (t < 10)  { float c = (float)(t - 2) * (1.0f / 7.0f);  float df = (cl - c) / 0.200001f; v = expf(-0.5f * df * df); }
        else if (t < 18)  { float c = (float)(t - 10) * (1.0f / 7.0f); float df = (cs - c) / 0.200001f; v = expf(-0.5f * df * df); }
        zr[512 + t] = (t < 18) ? f2bf(v) : 0;
    }
}

// ---------------- sink row ----------------
__global__ __launch_bounds__(256) void sink_kernel(
    const float* __restrict__ c_sink, const int* __restrict__ lengths,
    const float* __restrict__ beta_p, const float* __restrict__ floor_p,
    const float* __restrict__ gamma_p, float* __restrict__ srow)
{
    int i = blockIdx.x * 256 + threadIdx.x;
    int b = i >> 10, k = i & 1023;
    float beta = *beta_p, flr = *floor_p, gmm = *gamma_p;
    float cs = c_sink[i]; cs = fminf(fmaxf(cs, 0.f), 1.f);
    float v = beta * (flr + (1.f - flr) * powf(cs + 1e-6f, gmm));
    srow[i] = (k < lengths[b]) ? v : 0.f;
}

// ---------------- delay feature encoder: e[B,D] ----------------
__global__ __launch_bounds__(512) void delay_kernel(
    const float* __restrict__ delay, const float* __restrict__ w1, const float* __restrict__ b1,
    const float* __restrict__ w2, const float* __restrict__ b2,
    const float* __restrict__ lng, const float* __restrict__ lnb,
    float* __restrict__ e)
{
    int b = blockIdx.x;
    int t = threadIdx.x;
    __shared__ float g1[DD];
    __shared__ float red[16];
    float t1 = delay[b] * w1[t] + b1[t];
    g1[t] = gelu_exact(t1);
    __syncthreads();
    const float* wr = w2 + (size_t)t * DD;
    float s = b2[t];
    for (int j = 0; j < DD; j += 4) {
        float4 w4 = *(const float4*)(wr + j);
        s += w4.x * g1[j] + w4.y * g1[j+1] + w4.z * g1[j+2] + w4.w * g1[j+3];
    }
    float rs = wave_reduce_sum(s);
    float rss = wave_reduce_sum(s * s);
    int lane = t & 63, w = t >> 6;
    if (lane == 0) { red[w] = rs; red[8 + w] = rss; }
    __syncthreads();
    float mean = 0.f, msq = 0.f;
    #pragma unroll
    for (int i = 0; i < 8; ++i) { mean += red[i]; msq += red[8 + i]; }
    mean *= (1.0f / DD); msq *= (1.0f / DD);
    float rstd = rsqrtf(msq - mean * mean + 1e-5f);
    e[(size_t)b * DD + t] = (s - mean) * rstd * lng[t] + lnb[t];
}

// ---- templated MFMA GEMM: out[M,N] = epilogue(A[M,K] @ W[N,K]^T + bias) ----
// 4 waves in WGM x WGN grid (WGM = 4/WGN); per-wave FM x FN 16x16 fragments.
// global_load_lds staging, linear [R][32] LDS + XOR chunk swizzle both sides.
// MODE 0: f32 out ; 1: bf16 out ; 2: f32 out + resid ; 3: bf16 gelu
template<int BM, int BN, int FM, int FN, int WGN, int MODE>
__global__ __launch_bounds__(256) void gemm_t(
    const unsigned short* __restrict__ A, const unsigned short* __restrict__ W,
    const float* __restrict__ bias, const float* __restrict__ resid,
    float* __restrict__ outf, unsigned short* __restrict__ outb,
    int M, int N, int K)
{
    __shared__ __align__(16) unsigned short As[BM * 32];
    __shared__ __align__(16) unsigned short Ws[BN * 32];
    int bm = blockIdx.y * BM, bn = blockIdx.x * BN;
    int t = threadIdx.x;
    int lane = t & 63, wid = t >> 6;
    int wr = wid / WGN, wc = wid % WGN;
    int l15 = lane & 15, lg = lane >> 4;
    int srow = lane >> 2;
    int sc8 = ((lane & 3) ^ ((lane >> 2) & 3) ^ ((lane >> 4) & 3)) * 8;
    int chunk8 = (lg ^ (l15 & 3) ^ ((l15 >> 2) & 3)) * 8;

    f32x4 acc[FM][FN] = {};
    int nk = K >> 5;

    for (int ks = 0; ks < nk; ++ks) {
        int kb = ks * 32;
        #pragma unroll
        for (int i = 0; i < BM / 64; ++i) {
            int row = wid * (BM / 4) + i * 16 + srow;
            gload16(A + (size_t)(bm + row) * K + kb + sc8, &As[(wid * (BM / 64) + i) * 512]);
        }
        #pragma unroll
        for (int i = 0; i < BN / 64; ++i) {
            int row = wid * (BN / 4) + i * 16 + srow;
            gload16(W + (size_t)(bn + row) * K + kb + sc8, &Ws[(wid * (BN / 64) + i) * 512]);
        }
        __syncthreads();
        s16x8 af[FM], wf[FN];
        #pragma unroll
        for (int mi = 0; mi < FM; ++mi)
            af[mi] = *(const s16x8*)&As[(wr * FM * 16 + mi * 16 + l15) * 32 + chunk8];
        #pragma unroll
        for (int ni = 0; ni < FN; ++ni)
            wf[ni] = *(const s16x8*)&Ws[(wc * FN * 16 + ni * 16 + l15) * 32 + chunk8];
        #pragma unroll
        for (int mi = 0; mi < FM; ++mi)
            #pragma unroll
            for (int ni = 0; ni < FN; ++ni)
                acc[mi][ni] = __builtin_amdgcn_mfma_f32_16x16x32_bf16(af[mi], wf[ni], acc[mi][ni], 0, 0, 0);
        __syncthreads();
    }

    int rbase = (lane >> 4) * 4;
    #pragma unroll
    for (int mi = 0; mi < FM; ++mi) {
        #pragma unroll
        for (int ni = 0; ni < FN; ++ni) {
            int n = bn + wc * FN * 16 + ni * 16 + l15;
            float bz = bias[n];
            #pragma unroll
            for (int r2 = 0; r2 < 4; ++r2) {
                int m = bm + wr * FM * 16 + mi * 16 + rbase + r2;
                float v = acc[mi][ni][r2] + bz;
                size_t o = (size_t)m * N + n;
                if (MODE == 0)      outf[o] = v;
                else if (MODE == 1) outb[o] = f2bf(v);
                else if (MODE == 2) outf[o] = v + resid[o];
                else                outb[o] = f2bf(gelu_exact(v));
            }
        }
    }
}

// ---- V transpose: qkv V part -> Vt[b][h][d][l] ----
__global__ __launch_bounds__(256) void vtrans_kernel(
    const unsigned short* __restrict__ qkv, unsigned short* __restrict__ Vt)
{
    __shared__ unsigned short Ts[64 * 68];
    int l0 = blockIdx.x * 64;
    int hh = blockIdx.y;
    int b  = blockIdx.z;
    int t  = threadIdx.x;
    #pragma unroll
    for (int u = 0; u < 2; ++u) {
        int idx = t + u * 256;
        int r = idx >> 3, c8 = idx & 7;
        uint4 v = *(const uint4*)(qkv + (size_t)(b * LL + l0 + r) * 1536 + 1024 + hh * DH + c8 * 8);
        *(uint4*)&Ts[r * 68 + c8 * 8] = v;
    }
    __syncthreads();
    #pragma unroll
    for (int u = 0; u < 2; ++u) {
        int d = (t >> 3) + u * 32;
        int c = t & 7;
        unsigned short tmp[8];
        #pragma unroll
        for (int j = 0; j < 8; ++j) tmp[j] = Ts[(c * 8 + j) * 68 + d];
        *(uint4*)(Vt + ((size_t)((b * HH + hh) * DH + d)) * LL + l0 + c * 8) = *(const uint4*)tmp;
    }
}

// ------------- MFMA flash attention: block = (b, h, 64-q tile), 4 waves -------------
#define SK 72
#define SPB 72
__global__ __launch_bounds__(256) void attn_mfma(
    const unsigned short* __restrict__ qkv, const unsigned short* __restrict__ Vt,
    const float* __restrict__ c_local, const float* __restrict__ srow,
    const int* __restrict__ lengths,
    const float* __restrict__ alpha_p,
    unsigned short* __restrict__ o)
{
    __shared__ __align__(16) unsigned short Ks[64 * SK];
    __shared__ __align__(16) unsigned short Vts[64 * SK];
    __shared__ __align__(16) unsigned short Psb[64 * SPB];

    int q0 = blockIdx.x * 64;
    int hh = blockIdx.y;
    int b  = blockIdx.z;
    int t  = threadIdx.x;
    int lane = t & 63, w = t >> 6;
    int l15 = lane & 15, lg = lane >> 4;
    int len = lengths[b];
    const float alpha = *alpha_p;

    const unsigned short* qrow = qkv + (size_t)(b * LL + q0 + w * 16 + l15) * 1536 + hh * DH;
    s16x8 qf0 = *(const s16x8*)(qrow + lg * 8);
    s16x8 qf1 = *(const s16x8*)(qrow + 32 + lg * 8);

    float cm1[4], cp1[4];
    #pragma unroll
    for (int r2 = 0; r2 < 4; ++r2) {
        int qi = q0 + w * 16 + lg * 4 + r2;
        cm1[r2] = 0.f; cp1[r2] = 0.f;
        if (qi >= 1 && qi < len) {
            int src = (qi == 1 || qi == LL - 1) ? qi : qi - 1;
            cm1[r2] = alpha * c_local[(size_t)b * LL + src];
        }
        if (qi + 1 < LL && qi < len)
            cp1[r2] = alpha * c_local[(size_t)b * LL + qi + 1];
    }
    bool need_sink = (q0 == 0 && w == 0 && lg == 0);

    float m_run[4], l_run[4];
    f32x4 accO[4] = {};
    #pragma unroll
    for (int r2 = 0; r2 < 4; ++r2) { m_run[r2] = -1e30f; l_run[r2] = 0.f; }

    int sr = t >> 3, sc8 = (t & 7) * 8;
    const unsigned short* kbase = qkv + (size_t)(b * LL) * 1536 + 512 + hh * DH;
    const unsigned short* vbase = Vt + ((size_t)((b * HH + hh) * DH)) * LL;

    uint4 pk0 = *(const uint4*)(kbase + (size_t)sr * 1536 + sc8);
    uint4 pk1 = *(const uint4*)(kbase + (size_t)(sr + 32) * 1536 + sc8);
    uint4 pv0 = *(const uint4*)(vbase + (size_t)sr * LL + sc8);
    uint4 pv1 = *(const uint4*)(vbase + (size_t)(sr + 32) * LL + sc8);

    for (int k0 = 0; k0 < LL; k0 += 64) {
        *(uint4*)&Ks[sr * SK + sc8]         = pk0;
        *(uint4*)&Ks[(sr + 32) * SK + sc8]  = pk1;
        *(uint4*)&Vts[sr * SK + sc8]        = pv0;
        *(uint4*)&Vts[(sr + 32) * SK + sc8] = pv1;
        if (k0 + 64 < LL) {
            pk0 = *(const uint4*)(kbase + (size_t)(k0 + 64 + sr) * 1536 + sc8);
            pk1 = *(const uint4*)(kbase + (size_t)(k0 + 64 + sr + 32) * 1536 + sc8);
            pv0 = *(const uint4*)(vbase + (size_t)sr * LL + k0 + 64 + sc8);
            pv1 = *(const uint4*)(vbase + (size_t)(sr + 32) * LL + k0 + 64 + sc8);
        }
        __syncthreads();

        f32x4 accS[4] = {};
        #pragma unroll
        for (int ct = 0; ct < 4; ++ct) {
            s16x8 kf0 = *(const s16x8*)&Ks[(ct * 16 + l15) * SK + lg * 8];
            s16x8 kf1 = *(const s16x8*)&Ks[(ct * 16 + l15) * SK + 32 + lg * 8];
            accS[ct] = __builtin_amdgcn_mfma_f32_16x16x32_bf16(qf0, kf0, accS[ct], 0, 0, 0);
            accS[ct] = __builtin_amdgcn_mfma_f32_16x16x32_bf16(qf1, kf1, accS[ct], 0, 0, 0);
        }

        float m4[4] = { -1e30f, -1e30f, -1e30f, -1e30f };
        #pragma unroll
        for (int ct = 0; ct < 4; ++ct) {
            int k = k0 + ct * 16 + l15;
            bool maskk = (k >= len);
            float sink_ct = need_sink ? srow[(size_t)b * LL + k] : 0.f;
            #pragma unroll
            for (int r2 = 0; r2 < 4; ++r2) {
                int qi = q0 + w * 16 + lg * 4 + r2;
                float v = accS[ct][r2] * 0.125f;
                if (k == qi - 1) v += cm1[r2];
                else if (k == qi + 1 && !maskk) v += cp1[r2];
                if (r2 == 0) v += sink_ct;
                if (maskk) v -= 10000.f;
                accS[ct][r2] = v;
                m4[r2] = fmaxf(m4[r2], v);
            }
        }
        #pragma unroll
        for (int r2 = 0; r2 < 4; ++r2) {
            #pragma unroll
            for (int msk = 1; msk < 16; msk <<= 1) m4[r2] = fmaxf(m4[r2], __shfl_xor(m4[r2], msk));
            float mnew = fmaxf(m_run[r2], m4[r2]);
            float scl = __expf(m_run[r2] - mnew);
            m_run[r2] = mnew;
            float rowsum = 0.f;
            #pragma unroll
            for (int ct = 0; ct < 4; ++ct) {
                float p = __expf(accS[ct][r2] - mnew);
                rowsum += p;
                Psb[(w * 16 + lg * 4 + r2) * SPB + ct * 16 + l15] = f2bf(p);
            }
            #pragma unroll
            for (int msk = 1; msk < 16; msk <<= 1) rowsum += __shfl_xor(rowsum, msk);
            l_run[r2] = l_run[r2] * scl + rowsum;
            #pragma unroll
            for (int dt = 0; dt < 4; ++dt) accO[dt][r2] *= scl;
        }

        #pragma unroll
        for (int kk = 0; kk < 2; ++kk) {
            s16x8 pf = *(const s16x8*)&Psb[(w * 16 + l15) * SPB + kk * 32 + lg * 8];
            #pragma unroll
            for (int dt = 0; dt < 4; ++dt) {
                s16x8 vf = *(const s16x8*)&Vts[(dt * 16 + l15) * SK + kk * 32 + lg * 8];
                accO[dt] = __builtin_amdgcn_mfma_f32_16x16x32_bf16(pf, vf, accO[dt], 0, 0, 0);
            }
        }
        __syncthreads();
    }

    #pragma unroll
    for (int r2 = 0; r2 < 4; ++r2) {
        float inv = 1.f / l_run[r2];
        int qi = q0 + w * 16 + lg * 4 + r2;
        #pragma unroll
        for (int dt = 0; dt < 4; ++dt)
            o[(size_t)(b * LL + qi) * DD + hh * DH + dt * 16 + l15] = f2bf(accO[dt][r2] * inv);
    }
}

// ------ embed epilogue: h += e + mask?0:gain*LN(cpe_pre) ------
__global__ __launch_bounds__(256) void embed_ep_kernel(
    const float* __restrict__ cpe_pre, const float* __restrict__ e,
    const int* __restrict__ lengths,
    const float* __restrict__ cpe_g, const float* __restrict__ cpe_lb,
    const float* __restrict__ gain_p, float* __restrict__ h)
{
    int row = blockIdx.x;
    int b = row >> 10, l = row & 1023;
    int t = threadIdx.x;
    __shared__ float red[16];
    const float* cp = cpe_pre + (size_t)row * DD;
    float v0 = cp[t], v1 = cp[t + 256];
    float s = v0 + v1, ss = v0 * v0 + v1 * v1;
    float rs = wave_reduce_sum(s), rss = wave_reduce_sum(ss);
    int lane = t & 63, w = t >> 6;
    if (lane == 0) { red[w] = rs; red[8 + w] = rss; }
    __syncthreads();
    float mean = 0.f, msq = 0.f;
    #pragma unroll
    for (int i = 0; i < 4; ++i) { mean += red[i]; msq += red[8 + i]; }
    mean *= (1.0f / DD); msq *= (1.0f / DD);
    float rstd = rsqrtf(msq - mean * mean + 1e-5f);
    bool maskp = (l >= lengths[b]);
    float gain = *gain_p;
    float pe0 = maskp ? 0.f : gain * ((v0 - mean) * rstd * cpe_g[t] + cpe_lb[t]);
    float pe1 = maskp ? 0.f : gain * ((v1 - mean) * rstd * cpe_g[t + 256] + cpe_lb[t + 256]);
    h[(size_t)row * DD + t]       += e[(size_t)b * DD + t] + pe0;
    h[(size_t)row * DD + t + 256] += e[(size_t)b * DD + t + 256] + pe1;
}

// ---------------- LayerNorm f32 out (final) ----------------
__global__ __launch_bounds__(256) void ln_kernel(
    const float* __restrict__ in, float* __restrict__ out,
    const float* __restrict__ g, const float* __restrict__ bta)
{
    int row = blockIdx.x; int t = threadIdx.x;
    __shared__ float red[16];
    const float* xr = in + (size_t)row * DD;
    float2 v = ((const float2*)xr)[t];
    float s = v.x + v.y, ss = v.x * v.x + v.y * v.y;
    float rs = wave_reduce_sum(s), rss = wave_reduce_sum(ss);
    int lane = t & 63, w = t >> 6;
    if (lane == 0) { red[w] = rs; red[8 + w] = rss; }
    __syncthreads();
    float mean = 0.f, msq = 0.f;
    #pragma unroll
    for (int i = 0; i < 4; ++i) { mean += red[i]; msq += red[8 + i]; }
    mean *= (1.0f / DD); msq *= (1.0f / DD);
    float rstd = rsqrtf(msq - mean * mean + 1e-5f);
    float2 gg = ((const float2*)g)[t], bb = ((const float2*)bta)[t];
    float2 o;
    o.x = (v.x - mean) * rstd * gg.x + bb.x;
    o.y = (v.y - mean) * rstd * gg.y + bb.y;
    ((float2*)(out + (size_t)row * DD))[t] = o;
}

// ---------------- LayerNorm bf16 out ----------------
__global__ __launch_bounds__(256) void ln_bf16_kernel(
    const float* __restrict__ in, unsigned short* __restrict__ out,
    const float* __restrict__ g, const float* __restrict__ bta)
{
    int row = blockIdx.x; int t = threadIdx.x;
    __shared__ float red[16];
    const float* xr = in + (size_t)row * DD;
    float2 v = ((const float2*)xr)[t];
    float s = v.x + v.y, ss = v.x * v.x + v.y * v.y;
    float rs = wave_reduce_sum(s), rss = wave_reduce_sum(ss);
    int lane = t & 63, w = t >> 6;
    if (lane == 0) { red[w] = rs; red[8 + w] = rss; }
    __syncthreads();
    float mean = 0.f, msq = 0.f;
    #pragma unroll
    for (int i = 0; i < 4; ++i) { mean += red[i]; msq += red[8 + i]; }
    mean *= (1.0f / DD); msq *= (1.0f / DD);
    float rstd = rsqrtf(msq - mean * mean + 1e-5f);
    float2 gg = ((const float2*)g)[t], bb = ((const float2*)bta)[t];
    ushort2 o;
    o.x = f2bf((v.x - mean) * rstd * gg.x + bb.x);
    o.y = f2bf((v.y - mean) * rstd * gg.y + bb.y);
    ((ushort2*)(out + (size_t)row * DD))[t] = o;
}

extern "C" void kernel_launch(void* const* d_in, const int* in_sizes, int n_in,
                              void* d_out, int out_size, void* d_ws, size_t ws_size,
                              hipStream_t stream)
{
    const float* x          = (const float*)d_in[0];
    const int*   lengths    = (const int*)  d_in[1];
    const float* input_delay= (const float*)d_in[2];
    const float* c_local    = (const float*)d_in[3];
    const float* c_sink     = (const float*)d_in[4];
    const float* in_w       = (const float*)d_in[5];
    const float* in_b       = (const float*)d_in[6];
    const float* de_w1      = (const float*)d_in[7];
    const float* de_b1      = (const float*)d_in[8];
    const float* de_w2      = (const float*)d_in[9];
    const float* de_b2      = (const float*)d_in[10];
    const float* de_ln_g    = (const float*)d_in[11];
    const float* de_ln_b    = (const float*)d_in[12];
    const float* cpe_w      = (const float*)d_in[13];
    const float* cpe_b      = (const float*)d_in[14];
    const float* cpe_ln_g   = (const float*)d_in[15];
    const float* cpe_ln_b   = (const float*)d_in[16];
    const float* gain       = (const float*)d_in[17];
    const float* alpha      = (const float*)d_in[18];
    const float* beta       = (const float*)d_in[19];
    const float* floorp     = (const float*)d_in[20];
    const float* gammap     = (const float*)d_in[21];
    const float* inproj_w   = (const float*)d_in[22];
    const float* inproj_b   = (const float*)d_in[23];
    const float* outproj_w  = (const float*)d_in[24];
    const float* outproj_b  = (const float*)d_in[25];
    const float* ln1_g      = (const float*)d_in[26];
    const float* ln1_b      = (const float*)d_in[27];
    const float* ln2_g      = (const float*)d_in[28];
    const float* ln2_b      = (const float*)d_in[29];
    const float* ff_w1      = (const float*)d_in[30];
    const float* ff_b1      = (const float*)d_in[31];
    const float* ff_w2      = (const float*)d_in[32];
    const float* ff_b2      = (const float*)d_in[33];
    const float* out_ln_g   = (const float*)d_in[34];
    const float* out_ln_b   = (const float*)d_in[35];

    char* base = (char*)d_ws;
    float* h            = (float*)base;                               // 8 MB
    unsigned short* act1 = (unsigned short*)(base + 8u*1024*1024);    // 4 MB
    char* bigb          = base + 12u*1024*1024;                       // 16 MB shared region
    unsigned short* qkvb = (unsigned short*)bigb;                     // 12 MB (attn phase)
    unsigned short* vtb  = (unsigned short*)(bigb + 12u*1024*1024);   // 4 MB  (attn phase)
    unsigned short* ffb  = (unsigned short*)bigb;                     // 16 MB (FF phase)
    unsigned short* Zb   = (unsigned short*)bigb;                     // 4.46 MB (embed phase)
    unsigned short* x_bf = (unsigned short*)(bigb + 5u*1024*1024);    // 0.5 MB
    float* cpe_pre       = (float*)(bigb + 8u*1024*1024);             // 8 MB
    unsigned short* w_inproj  = (unsigned short*)(base + 28u*1024*1024);
    unsigned short* w_outproj = w_inproj  + (size_t)3*1536*512;
    unsigned short* w_ff1     = w_outproj + (size_t)3*512*512;
    unsigned short* w_ff2     = w_ff1     + (size_t)3*2048*512;
    unsigned short* w_in      = w_ff2     + (size_t)3*512*2048;
    unsigned short* w_cpe     = w_in      + (size_t)512*64;
    float* e                  = (float*)(w_cpe + (size_t)512*544);
    float* srow               = e + (size_t)BB*DD;

    // weight / input conversions (every launch; deterministic)
    cvt_kernel<<<128, 256, 0, stream>>>(x, x_bf, MM * DIN);
    cvt_kernel<<<2048, 256, 0, stream>>>(inproj_w, w_inproj, 3 * 1536 * 512);
    cvt_kernel<<<1024, 256, 0, stream>>>(outproj_w, w_outproj, 3 * 512 * 512);
    cvt_kernel<<<2048, 256, 0, stream>>>(ff_w1, w_ff1, 3 * 2048 * 512);
    cvt_kernel<<<2048, 256, 0, stream>>>(ff_w2, w_ff2, 3 * 512 * 2048);
    cvt_kernel<<<64, 256, 0, stream>>>(in_w, w_in, 512 * 64);
    cpe_pad_kernel<<<1024, 256, 0, stream>>>(cpe_w, w_cpe);

    delay_kernel<<<BB, 512, 0, stream>>>(input_delay, de_w1, de_b1, de_w2, de_b2, de_ln_g, de_ln_b, e);
    build_z_kernel<<<MM, 256, 0, stream>>>(c_local, c_sink, Zb);
    sink_kernel<<<BB * LL / 256, 256, 0, stream>>>(c_sink, lengths, beta, floorp, gammap, srow);

    // h0 = x @ in_w^T + in_b   (64x64 tiles -> 512 blocks)
    gemm_t<64, 64, 2, 2, 2, 0><<<dim3(DD / 64, MM / 64), 256, 0, stream>>>(
        x_bf, w_in, in_b, nullptr, h, nullptr, MM, DD, DIN);
    // cpe_pre = Z @ cpe_w^T + cpe_b
    gemm_t<64, 64, 2, 2, 2, 0><<<dim3(DD / 64, MM / 64), 256, 0, stream>>>(
        Zb, w_cpe, cpe_b, nullptr, cpe_pre, nullptr, MM, DD, FEATP);
    embed_ep_kernel<<<MM, 256, 0, stream>>>(cpe_pre, e, lengths, cpe_ln_g, cpe_ln_b, gain, h);

    for (int i = 0; i < NLAYER; ++i) {
        ln_bf16_kernel<<<MM, 256, 0, stream>>>(h, act1, ln1_g + (size_t)i * DD, ln1_b + (size_t)i * DD);
        // qkv: 64x128 tiles -> 768 blocks (3/CU)
        gemm_t<64, 128, 2, 4, 2, 1><<<dim3(1536 / 128, MM / 64), 256, 0, stream>>>(
            act1, w_inproj + (size_t)i * 1536 * 512, inproj_b + (size_t)i * 1536,
            nullptr, nullptr, qkvb, MM, 1536, DD);
        vtrans_kernel<<<dim3(LL / 64, HH, BB), 256, 0, stream>>>(qkvb, vtb);
        attn_mfma<<<dim3(LL / 64, HH, BB), 256, 0, stream>>>(qkvb, vtb, c_local, srow, lengths,
                                                             alpha, act1);
        // outproj (+resid): 64x64 -> 512 blocks
        gemm_t<64, 64, 2, 2, 2, 2><<<dim3(DD / 64, MM / 64), 256, 0, stream>>>(
            act1, w_outproj + (size_t)i * 512 * 512, outproj_b + (size_t)i * DD,
            h, h, nullptr, MM, DD, DD);
        ln_bf16_kernel<<<MM, 256, 0, stream>>>(h, act1, ln2_g + (size_t)i * DD, ln2_b + (size_t)i * DD);
        // FF1 (gelu): 128x128 -> 512 blocks
        gemm_t<128, 128, 4, 4, 2, 3><<<dim3(DFF / 128, MM / 128), 256, 0, stream>>>(
            act1, w_ff1 + (size_t)i * 2048 * 512, ff_b1 + (size_t)i * DFF,
            nullptr, nullptr, ffb, MM, DFF, DD);
        // FF2 (+resid): 64x64 -> 512 blocks
        gemm_t<64, 64, 2, 2, 2, 2><<<dim3(DD / 64, MM / 64), 256, 0, stream>>>(
            ffb, w_ff2 + (size_t)i * 512 * 2048, ff_b2 + (size_t)i * DD,
            h, h, nullptr, MM, DD, DFF);
    }
    ln_kernel<<<MM, 256, 0, stream>>>(h, (float*)d_out, out_ln_g, out_ln_b);
}

// Round 8
// 484.751 us; speedup vs baseline: 12.4744x; 1.0753x over previous
//
#include <hip/hip_runtime.h>
#include <math.h>

#define BB 4
#define LL 1024
#define DIN 64
#define DD 512
#define HH 8
#define DH 64
#define NLAYER 3
#define DFF 2048
#define FEAT 530
#define FEATP 544
#define MM 4096

typedef float f32x4 __attribute__((ext_vector_type(4)));
typedef short s16x8 __attribute__((ext_vector_type(8)));

__device__ __forceinline__ unsigned short f2bf(float f) {
    unsigned int u = __float_as_uint(f);
    u += 0x7fffu + ((u >> 16) & 1u);
    return (unsigned short)(u >> 16);
}
__device__ __forceinline__ float bf2f(unsigned short u) {
    return __uint_as_float(((unsigned int)u) << 16);
}
__device__ __forceinline__ float gelu_exact(float x) {
    return 0.5f * x * (1.0f + erff(x * 0.7071067811865475f));
}
__device__ __forceinline__ float wave_reduce_sum(float v) {
    #pragma unroll
    for (int o = 32; o; o >>= 1) v += __shfl_down(v, o);
    return v;
}
__device__ __forceinline__ void gload16(const unsigned short* g, unsigned short* l) {
    __builtin_amdgcn_global_load_lds(
        (const __attribute__((address_space(1))) unsigned int*)g,
        (__attribute__((address_space(3))) unsigned int*)l, 16, 0, 0);
}

// ---------------- generic f32 -> bf16 convert ----------------
__global__ __launch_bounds__(256) void cvt_kernel(
    const float* __restrict__ in, unsigned short* __restrict__ out, int n)
{
    for (int i = blockIdx.x * 256 + threadIdx.x; i < n; i += gridDim.x * 256)
        out[i] = f2bf(in[i]);
}

// ---------------- cpe_w [512][530] f32 -> [512][544] bf16 (zero pad) ----------------
__global__ __launch_bounds__(256) void cpe_pad_kernel(
    const float* __restrict__ in, unsigned short* __restrict__ out)
{
    for (int i = blockIdx.x * 256 + threadIdx.x; i < DD * FEATP; i += gridDim.x * 256) {
        int r = i / FEATP, c = i - r * FEATP;
        out[i] = (c < FEAT) ? f2bf(in[(size_t)r * FEAT + c]) : 0;
    }
}

// ---------------- build Z[M][544] bf16: PE + raw + RBFs ----------------
__global__ __launch_bounds__(256) void build_z_kernel(
    const float* __restrict__ c_local, const float* __restrict__ c_sink,
    unsigned short* __restrict__ Z)
{
    int row = blockIdx.x;
    int b = row >> 10, l = row & 1023;
    int t = threadIdx.x;
    unsigned short* zr = Z + (size_t)row * FEATP;
    for (int d = t; d < DD; d += 256) {
        int i = d >> 1;
        float dv = expf((float)(2 * i) * (-0.017988946135618352f)); // -ln(1e4)/512
        float ang = (float)l * dv;
        zr[d] = f2bf((d & 1) ? cosf(ang) : sinf(ang));
    }
    if (t < 32) {
        float cl = c_local[(size_t)b * LL + l]; cl = fminf(fmaxf(cl, 0.f), 1.f);
        float cs = c_sink [(size_t)b * LL + l]; cs = fminf(fmaxf(cs, 0.f), 1.f);
        float v = 0.f;
        if (t == 0) v = cl;
        else if (t == 1) v = cs;
        else if (t < 10)  { float c = (float)(t - 2) * (1.0f / 7.0f);  float df = (cl - c) / 0.200001f; v = expf(-0.5f * df * df); }
        else if (t < 18)  { float c = (float)(t - 10) * (1.0f / 7.0f); float df = (cs - c) / 0.200001f; v = expf(-0.5f * df * df); }
        zr[512 + t] = (t < 18) ? f2bf(v) : 0;
    }
}

// ---------------- sink row ----------------
__global__ __launch_bounds__(256) void sink_kernel(
    const float* __restrict__ c_sink, const int* __restrict__ lengths,
    const float* __restrict__ beta_p, const float* __restrict__ floor_p,
    const float* __restrict__ gamma_p, float* __restrict__ srow)
{
    int i = blockIdx.x * 256 + threadIdx.x;
    int b = i >> 10, k = i & 1023;
    float beta = *beta_p, flr = *floor_p, gmm = *gamma_p;
    float cs = c_sink[i]; cs = fminf(fmaxf(cs, 0.f), 1.f);
    float v = beta * (flr + (1.f - flr) * powf(cs + 1e-6f, gmm));
    srow[i] = (k < lengths[b]) ? v : 0.f;
}

// ---------------- delay feature encoder: e[B,D] ----------------
__global__ __launch_bounds__(512) void delay_kernel(
    const float* __restrict__ delay, const float* __restrict__ w1, const float* __restrict__ b1,
    const float* __restrict__ w2, const float* __restrict__ b2,
    const float* __restrict__ lng, const float* __restrict__ lnb,
    float* __restrict__ e)
{
    int b = blockIdx.x;
    int t = threadIdx.x;
    __shared__ float g1[DD];
    __shared__ float red[16];
    float t1 = delay[b] * w1[t] + b1[t];
    g1[t] = gelu_exact(t1);
    __syncthreads();
    const float* wr = w2 + (size_t)t * DD;
    float s = b2[t];
    for (int j = 0; j < DD; j += 4) {
        float4 w4 = *(const float4*)(wr + j);
        s += w4.x * g1[j] + w4.y * g1[j+1] + w4.z * g1[j+2] + w4.w * g1[j+3];
    }
    float rs = wave_reduce_sum(s);
    float rss = wave_reduce_sum(s * s);
    int lane = t & 63, w = t >> 6;
    if (lane == 0) { red[w] = rs; red[8 + w] = rss; }
    __syncthreads();
    float mean = 0.f, msq = 0.f;
    #pragma unroll
    for (int i = 0; i < 8; ++i) { mean += red[i]; msq += red[8 + i]; }
    mean *= (1.0f / DD); msq *= (1.0f / DD);
    float rstd = rsqrtf(msq - mean * mean + 1e-5f);
    e[(size_t)b * DD + t] = (s - mean) * rstd * lng[t] + lnb[t];
}

// ---- templated MFMA GEMM ----
template<int BM, int BN, int FM, int FN, int WGN, int MODE>
__global__ __launch_bounds__(256) void gemm_t(
    const unsigned short* __restrict__ A, const unsigned short* __restrict__ W,
    const float* __restrict__ bias, const float* __restrict__ resid,
    float* __restrict__ outf, unsigned short* __restrict__ outb,
    int M, int N, int K)
{
    __shared__ __align__(16) unsigned short As[BM * 32];
    __shared__ __align__(16) unsigned short Ws[BN * 32];
    int bm = blockIdx.y * BM, bn = blockIdx.x * BN;
    int t = threadIdx.x;
    int lane = t & 63, wid = t >> 6;
    int wr = wid / WGN, wc = wid % WGN;
    int l15 = lane & 15, lg = lane >> 4;
    int srow = lane >> 2;
    int sc8 = ((lane & 3) ^ ((lane >> 2) & 3) ^ ((lane >> 4) & 3)) * 8;
    int chunk8 = (lg ^ (l15 & 3) ^ ((l15 >> 2) & 3)) * 8;

    f32x4 acc[FM][FN] = {};
    int nk = K >> 5;

    for (int ks = 0; ks < nk; ++ks) {
        int kb = ks * 32;
        #pragma unroll
        for (int i = 0; i < BM / 64; ++i) {
            int row = wid * (BM / 4) + i * 16 + srow;
            gload16(A + (size_t)(bm + row) * K + kb + sc8, &As[(wid * (BM / 64) + i) * 512]);
        }
        #pragma unroll
        for (int i = 0; i < BN / 64; ++i) {
            int row = wid * (BN / 4) + i * 16 + srow;
            gload16(W + (size_t)(bn + row) * K + kb + sc8, &Ws[(wid * (BN / 64) + i) * 512]);
        }
        __syncthreads();
        s16x8 af[FM], wf[FN];
        #pragma unroll
        for (int mi = 0; mi < FM; ++mi)
            af[mi] = *(const s16x8*)&As[(wr * FM * 16 + mi * 16 + l15) * 32 + chunk8];
        #pragma unroll
        for (int ni = 0; ni < FN; ++ni)
            wf[ni] = *(const s16x8*)&Ws[(wc * FN * 16 + ni * 16 + l15) * 32 + chunk8];
        #pragma unroll
        for (int mi = 0; mi < FM; ++mi)
            #pragma unroll
            for (int ni = 0; ni < FN; ++ni)
                acc[mi][ni] = __builtin_amdgcn_mfma_f32_16x16x32_bf16(af[mi], wf[ni], acc[mi][ni], 0, 0, 0);
        __syncthreads();
    }

    int rbase = (lane >> 4) * 4;
    #pragma unroll
    for (int mi = 0; mi < FM; ++mi) {
        #pragma unroll
        for (int ni = 0; ni < FN; ++ni) {
            int n = bn + wc * FN * 16 + ni * 16 + l15;
            float bz = bias[n];
            #pragma unroll
            for (int r2 = 0; r2 < 4; ++r2) {
                int m = bm + wr * FM * 16 + mi * 16 + rbase + r2;
                float v = acc[mi][ni][r2] + bz;
                size_t o = (size_t)m * N + n;
                if (MODE == 0)      outf[o] = v;
                else if (MODE == 1) outb[o] = f2bf(v);
                else if (MODE == 2) outf[o] = v + resid[o];
                else                outb[o] = f2bf(gelu_exact(v));
            }
        }
    }
}

// ---- V transpose: qkv V part -> Vt[b][h][d][l] ----
__global__ __launch_bounds__(256) void vtrans_kernel(
    const unsigned short* __restrict__ qkv, unsigned short* __restrict__ Vt)
{
    __shared__ unsigned short Ts[64 * 68];
    int l0 = blockIdx.x * 64;
    int hh = blockIdx.y;
    int b  = blockIdx.z;
    int t  = threadIdx.x;
    #pragma unroll
    for (int u = 0; u < 2; ++u) {
        int idx = t + u * 256;
        int r = idx >> 3, c8 = idx & 7;
        uint4 v = *(const uint4*)(qkv + (size_t)(b * LL + l0 + r) * 1536 + 1024 + hh * DH + c8 * 8);
        *(uint4*)&Ts[r * 68 + c8 * 8] = v;
    }
    __syncthreads();
    #pragma unroll
    for (int u = 0; u < 2; ++u) {
        int d = (t >> 3) + u * 32;
        int c = t & 7;
        unsigned short tmp[8];
        #pragma unroll
        for (int j = 0; j < 8; ++j) tmp[j] = Ts[(c * 8 + j) * 68 + d];
        *(uint4*)(Vt + ((size_t)((b * HH + hh) * DH + d)) * LL + l0 + c * 8) = *(const uint4*)tmp;
    }
}

// ------------- MFMA flash attention: 1-D grid (XCD-swizzled), 4 waves -------------
#define SK 72
#define SPB 72
__global__ __launch_bounds__(256) void attn_mfma(
    const unsigned short* __restrict__ qkv, const unsigned short* __restrict__ Vt,
    const float* __restrict__ c_local, const float* __restrict__ srow,
    const int* __restrict__ lengths,
    const float* __restrict__ alpha_p,
    unsigned short* __restrict__ o)
{
    __shared__ __align__(16) unsigned short Ks[64 * SK];
    __shared__ __align__(16) unsigned short Vts[64 * SK];
    __shared__ __align__(16) unsigned short Psb[64 * SPB];

    // XCD swizzle: the 16 q-blocks sharing (b,h) land on one XCD
    int id = blockIdx.x;
    int swz = (id & 7) * 64 + (id >> 3);
    int q0 = (swz & 15) * 64;
    int hh = (swz >> 4) & 7;
    int b  = swz >> 7;

    int t  = threadIdx.x;
    int lane = t & 63, w = t >> 6;
    int l15 = lane & 15, lg = lane >> 4;
    int len = lengths[b];
    int nt = (len + 63) >> 6;          // masked k-tiles contribute ~exp(-20)≈2e-9 in ref: negligible
    const float alpha = *alpha_p;

    // Q fragments, pre-scaled by 1/8 (exact: exponent shift)
    const unsigned short* qrow = qkv + (size_t)(b * LL + q0 + w * 16 + l15) * 1536 + hh * DH;
    s16x8 qf0 = *(const s16x8*)(qrow + lg * 8);
    s16x8 qf1 = *(const s16x8*)(qrow + 32 + lg * 8);
    #pragma unroll
    for (int j = 0; j < 8; ++j) {
        qf0[j] = (short)f2bf(bf2f((unsigned short)qf0[j]) * 0.125f);
        qf1[j] = (short)f2bf(bf2f((unsigned short)qf1[j]) * 0.125f);
    }

    float cm1[4], cp1[4];
    #pragma unroll
    for (int r2 = 0; r2 < 4; ++r2) {
        int qi = q0 + w * 16 + lg * 4 + r2;
        cm1[r2] = 0.f; cp1[r2] = 0.f;
        if (qi >= 1 && qi < len) {
            int src = (qi == 1 || qi == LL - 1) ? qi : qi - 1;
            cm1[r2] = alpha * c_local[(size_t)b * LL + src];
        }
        if (qi + 1 < LL && qi < len)
            cp1[r2] = alpha * c_local[(size_t)b * LL + qi + 1];
    }
    bool need_sink = (q0 == 0 && w == 0 && lg == 0);

    float m_run[4], l_run[4];
    f32x4 accO[4] = {};
    #pragma unroll
    for (int r2 = 0; r2 < 4; ++r2) { m_run[r2] = -1e30f; l_run[r2] = 0.f; }

    int sr = t >> 3, sc8 = (t & 7) * 8;
    const unsigned short* kbase = qkv + (size_t)(b * LL) * 1536 + 512 + hh * DH;
    const unsigned short* vbase = Vt + ((size_t)((b * HH + hh) * DH)) * LL;

    uint4 pk0 = *(const uint4*)(kbase + (size_t)sr * 1536 + sc8);
    uint4 pk1 = *(const uint4*)(kbase + (size_t)(sr + 32) * 1536 + sc8);
    uint4 pv0 = *(const uint4*)(vbase + (size_t)sr * LL + sc8);
    uint4 pv1 = *(const uint4*)(vbase + (size_t)(sr + 32) * LL + sc8);

    for (int kt = 0; kt < nt; ++kt) {
        int k0 = kt * 64;
        *(uint4*)&Ks[sr * SK + sc8]         = pk0;
        *(uint4*)&Ks[(sr + 32) * SK + sc8]  = pk1;
        *(uint4*)&Vts[sr * SK + sc8]        = pv0;
        *(uint4*)&Vts[(sr + 32) * SK + sc8] = pv1;
        if (kt + 1 < nt) {
            int kn = k0 + 64;
            pk0 = *(const uint4*)(kbase + (size_t)(kn + sr) * 1536 + sc8);
            pk1 = *(const uint4*)(kbase + (size_t)(kn + sr + 32) * 1536 + sc8);
            pv0 = *(const uint4*)(vbase + (size_t)sr * LL + kn + sc8);
            pv1 = *(const uint4*)(vbase + (size_t)(sr + 32) * LL + kn + sc8);
        }
        __syncthreads();

        // S = Q K^T (pre-scaled)
        f32x4 accS[4] = {};
        #pragma unroll
        for (int ct = 0; ct < 4; ++ct) {
            s16x8 kf0 = *(const s16x8*)&Ks[(ct * 16 + l15) * SK + lg * 8];
            s16x8 kf1 = *(const s16x8*)&Ks[(ct * 16 + l15) * SK + 32 + lg * 8];
            accS[ct] = __builtin_amdgcn_mfma_f32_16x16x32_bf16(qf0, kf0, accS[ct], 0, 0, 0);
            accS[ct] = __builtin_amdgcn_mfma_f32_16x16x32_bf16(qf1, kf1, accS[ct], 0, 0, 0);
        }

        float m4[4] = { -1e30f, -1e30f, -1e30f, -1e30f };
        if (k0 + 64 <= len) {
            // interior tile: no mask ops
            #pragma unroll
            for (int ct = 0; ct < 4; ++ct) {
                int k = k0 + ct * 16 + l15;
                float sink_ct = need_sink ? srow[(size_t)b * LL + k] : 0.f;
                #pragma unroll
                for (int r2 = 0; r2 < 4; ++r2) {
                    int qi = q0 + w * 16 + lg * 4 + r2;
                    float v = accS[ct][r2];
                    if (k == qi - 1) v += cm1[r2];
                    else if (k == qi + 1) v += cp1[r2];
                    if (r2 == 0) v += sink_ct;
                    accS[ct][r2] = v;
                    m4[r2] = fmaxf(m4[r2], v);
                }
            }
        } else {
            // straddle tile
            #pragma unroll
            for (int ct = 0; ct < 4; ++ct) {
                int k = k0 + ct * 16 + l15;
                bool maskk = (k >= len);
                float sink_ct = need_sink ? srow[(size_t)b * LL + k] : 0.f;
                #pragma unroll
                for (int r2 = 0; r2 < 4; ++r2) {
                    int qi = q0 + w * 16 + lg * 4 + r2;
                    float v = accS[ct][r2];
                    if (k == qi - 1) v += cm1[r2];
                    else if (k == qi + 1 && !maskk) v += cp1[r2];
                    if (r2 == 0) v += sink_ct;
                    if (maskk) v -= 10000.f;
                    accS[ct][r2] = v;
                    m4[r2] = fmaxf(m4[r2], v);
                }
            }
        }

        #pragma unroll
        for (int r2 = 0; r2 < 4; ++r2) {
            #pragma unroll
            for (int msk = 1; msk < 16; msk <<= 1) m4[r2] = fmaxf(m4[r2], __shfl_xor(m4[r2], msk));
            float mnew = fmaxf(m_run[r2], m4[r2]);
            float scl = __expf(m_run[r2] - mnew);
            m_run[r2] = mnew;
            float rowsum = 0.f;
            #pragma unroll
            for (int ct = 0; ct < 4; ++ct) {
                float p = __expf(accS[ct][r2] - mnew);
                rowsum += p;
                Psb[(w * 16 + lg * 4 + r2) * SPB + ct * 16 + l15] = f2bf(p);
            }
            #pragma unroll
            for (int msk = 1; msk < 16; msk <<= 1) rowsum += __shfl_xor(rowsum, msk);
            l_run[r2] = l_run[r2] * scl + rowsum;
            #pragma unroll
            for (int dt = 0; dt < 4; ++dt) accO[dt][r2] *= scl;
        }

        // O += P @ V (wave-local P rows; bf16 fragments straight from LDS)
        #pragma unroll
        for (int kk = 0; kk < 2; ++kk) {
            s16x8 pf = *(const s16x8*)&Psb[(w * 16 + l15) * SPB + kk * 32 + lg * 8];
            #pragma unroll
            for (int dt = 0; dt < 4; ++dt) {
                s16x8 vf = *(const s16x8*)&Vts[(dt * 16 + l15) * SK + kk * 32 + lg * 8];
                accO[dt] = __builtin_amdgcn_mfma_f32_16x16x32_bf16(pf, vf, accO[dt], 0, 0, 0);
            }
        }
        __syncthreads();
    }

    #pragma unroll
    for (int r2 = 0; r2 < 4; ++r2) {
        float inv = 1.f / l_run[r2];
        int qi = q0 + w * 16 + lg * 4 + r2;
        #pragma unroll
        for (int dt = 0; dt < 4; ++dt)
            o[(size_t)(b * LL + qi) * DD + hh * DH + dt * 16 + l15] = f2bf(accO[dt][r2] * inv);
    }
}

// ------ embed epilogue: h += e + mask?0:gain*LN(cpe_pre) ------
__global__ __launch_bounds__(256) void embed_ep_kernel(
    const float* __restrict__ cpe_pre, const float* __restrict__ e,
    const int* __restrict__ lengths,
    const float* __restrict__ cpe_g, const float* __restrict__ cpe_lb,
    const float* __restrict__ gain_p, float* __restrict__ h)
{
    int row = blockIdx.x;
    int b = row >> 10, l = row & 1023;
    int t = threadIdx.x;
    __shared__ float red[16];
    const float* cp = cpe_pre + (size_t)row * DD;
    float v0 = cp[t], v1 = cp[t + 256];
    float s = v0 + v1, ss = v0 * v0 + v1 * v1;
    float rs = wave_reduce_sum(s), rss = wave_reduce_sum(ss);
    int lane = t & 63, w = t >> 6;
    if (lane == 0) { red[w] = rs; red[8 + w] = rss; }
    __syncthreads();
    float mean = 0.f, msq = 0.f;
    #pragma unroll
    for (int i = 0; i < 4; ++i) { mean += red[i]; msq += red[8 + i]; }
    mean *= (1.0f / DD); msq *= (1.0f / DD);
    float rstd = rsqrtf(msq - mean * mean + 1e-5f);
    bool maskp = (l >= lengths[b]);
    float gain = *gain_p;
    float pe0 = maskp ? 0.f : gain * ((v0 - mean) * rstd * cpe_g[t] + cpe_lb[t]);
    float pe1 = maskp ? 0.f : gain * ((v1 - mean) * rstd * cpe_g[t + 256] + cpe_lb[t + 256]);
    h[(size_t)row * DD + t]       += e[(size_t)b * DD + t] + pe0;
    h[(size_t)row * DD + t + 256] += e[(size_t)b * DD + t + 256] + pe1;
}

// ---------------- LayerNorm f32 out (final) ----------------
__global__ __launch_bounds__(256) void ln_kernel(
    const float* __restrict__ in, float* __restrict__ out,
    const float* __restrict__ g, const float* __restrict__ bta)
{
    int row = blockIdx.x; int t = threadIdx.x;
    __shared__ float red[16];
    const float* xr = in + (size_t)row * DD;
    float2 v = ((const float2*)xr)[t];
    float s = v.x + v.y, ss = v.x * v.x + v.y * v.y;
    float rs = wave_reduce_sum(s), rss = wave_reduce_sum(ss);
    int lane = t & 63, w = t >> 6;
    if (lane == 0) { red[w] = rs; red[8 + w] = rss; }
    __syncthreads();
    float mean = 0.f, msq = 0.f;
    #pragma unroll
    for (int i = 0; i < 4; ++i) { mean += red[i]; msq += red[8 + i]; }
    mean *= (1.0f / DD); msq *= (1.0f / DD);
    float rstd = rsqrtf(msq - mean * mean + 1e-5f);
    float2 gg = ((const float2*)g)[t], bb = ((const float2*)bta)[t];
    float2 o;
    o.x = (v.x - mean) * rstd * gg.x + bb.x;
    o.y = (v.y - mean) * rstd * gg.y + bb.y;
    ((float2*)(out + (size_t)row * DD))[t] = o;
}

// ---------------- LayerNorm bf16 out ----------------
__global__ __launch_bounds__(256) void ln_bf16_kernel(
    const float* __restrict__ in, unsigned short* __restrict__ out,
    const float* __restrict__ g, const float* __restrict__ bta)
{
    int row = blockIdx.x; int t = threadIdx.x;
    __shared__ float red[16];
    const float* xr = in + (size_t)row * DD;
    float2 v = ((const float2*)xr)[t];
    float s = v.x + v.y, ss = v.x * v.x + v.y * v.y;
    float rs = wave_reduce_sum(s), rss = wave_reduce_sum(ss);
    int lane = t & 63, w = t >> 6;
    if (lane == 0) { red[w] = rs; red[8 + w] = rss; }
    __syncthreads();
    float mean = 0.f, msq = 0.f;
    #pragma unroll
    for (int i = 0; i < 4; ++i) { mean += red[i]; msq += red[8 + i]; }
    mean *= (1.0f / DD); msq *= (1.0f / DD);
    float rstd = rsqrtf(msq - mean * mean + 1e-5f);
    float2 gg = ((const float2*)g)[t], bb = ((const float2*)bta)[t];
    ushort2 o;
    o.x = f2bf((v.x - mean) * rstd * gg.x + bb.x);
    o.y = f2bf((v.y - mean) * rstd * gg.y + bb.y);
    ((ushort2*)(out + (size_t)row * DD))[t] = o;
}

extern "C" void kernel_launch(void* const* d_in, const int* in_sizes, int n_in,
                              void* d_out, int out_size, void* d_ws, size_t ws_size,
                              hipStream_t stream)
{
    const float* x          = (const float*)d_in[0];
    const int*   lengths    = (const int*)  d_in[1];
    const float* input_delay= (const float*)d_in[2];
    const float* c_local    = (const float*)d_in[3];
    const float* c_sink     = (const float*)d_in[4];
    const float* in_w       = (const float*)d_in[5];
    const float* in_b       = (const float*)d_in[6];
    const float* de_w1      = (const float*)d_in[7];
    const float* de_b1      = (const float*)d_in[8];
    const float* de_w2      = (const float*)d_in[9];
    const float* de_b2      = (const float*)d_in[10];
    const float* de_ln_g    = (const float*)d_in[11];
    const float* de_ln_b    = (const float*)d_in[12];
    const float* cpe_w      = (const float*)d_in[13];
    const float* cpe_b      = (const float*)d_in[14];
    const float* cpe_ln_g   = (const float*)d_in[15];
    const float* cpe_ln_b   = (const float*)d_in[16];
    const float* gain       = (const float*)d_in[17];
    const float* alpha      = (const float*)d_in[18];
    const float* beta       = (const float*)d_in[19];
    const float* floorp     = (const float*)d_in[20];
    const float* gammap     = (const float*)d_in[21];
    const float* inproj_w   = (const float*)d_in[22];
    const float* inproj_b   = (const float*)d_in[23];
    const float* outproj_w  = (const float*)d_in[24];
    const float* outproj_b  = (const float*)d_in[25];
    const float* ln1_g      = (const float*)d_in[26];
    const float* ln1_b      = (const float*)d_in[27];
    const float* ln2_g      = (const float*)d_in[28];
    const float* ln2_b      = (const float*)d_in[29];
    const float* ff_w1      = (const float*)d_in[30];
    const float* ff_b1      = (const float*)d_in[31];
    const float* ff_w2      = (const float*)d_in[32];
    const float* ff_b2      = (const float*)d_in[33];
    const float* out_ln_g   = (const float*)d_in[34];
    const float* out_ln_b   = (const float*)d_in[35];

    char* base = (char*)d_ws;
    float* h            = (float*)base;                               // 8 MB
    unsigned short* act1 = (unsigned short*)(base + 8u*1024*1024);    // 4 MB
    char* bigb          = base + 12u*1024*1024;                       // 16 MB shared region
    unsigned short* qkvb = (unsigned short*)bigb;                     // 12 MB (attn phase)
    unsigned short* vtb  = (unsigned short*)(bigb + 12u*1024*1024);   // 4 MB  (attn phase)
    unsigned short* ffb  = (unsigned short*)bigb;                     // 16 MB (FF phase)
    unsigned short* Zb   = (unsigned short*)bigb;                     // 4.46 MB (embed phase)
    unsigned short* x_bf = (unsigned short*)(bigb + 5u*1024*1024);    // 0.5 MB
    float* cpe_pre       = (float*)(bigb + 8u*1024*1024);             // 8 MB
    unsigned short* w_inproj  = (unsigned short*)(base + 28u*1024*1024);
    unsigned short* w_outproj = w_inproj  + (size_t)3*1536*512;
    unsigned short* w_ff1     = w_outproj + (size_t)3*512*512;
    unsigned short* w_ff2     = w_ff1     + (size_t)3*2048*512;
    unsigned short* w_in      = w_ff2     + (size_t)3*512*2048;
    unsigned short* w_cpe     = w_in      + (size_t)512*64;
    float* e                  = (float*)(w_cpe + (size_t)512*544);
    float* srow               = e + (size_t)BB*DD;

    cvt_kernel<<<128, 256, 0, stream>>>(x, x_bf, MM * DIN);
    cvt_kernel<<<2048, 256, 0, stream>>>(inproj_w, w_inproj, 3 * 1536 * 512);
    cvt_kernel<<<1024, 256, 0, stream>>>(outproj_w, w_outproj, 3 * 512 * 512);
    cvt_kernel<<<2048, 256, 0, stream>>>(ff_w1, w_ff1, 3 * 2048 * 512);
    cvt_kernel<<<2048, 256, 0, stream>>>(ff_w2, w_ff2, 3 * 512 * 2048);
    cvt_kernel<<<64, 256, 0, stream>>>(in_w, w_in, 512 * 64);
    cpe_pad_kernel<<<1024, 256, 0, stream>>>(cpe_w, w_cpe);

    delay_kernel<<<BB, 512, 0, stream>>>(input_delay, de_w1, de_b1, de_w2, de_b2, de_ln_g, de_ln_b, e);
    build_z_kernel<<<MM, 256, 0, stream>>>(c_local, c_sink, Zb);
    sink_kernel<<<BB * LL / 256, 256, 0, stream>>>(c_sink, lengths, beta, floorp, gammap, srow);

    gemm_t<64, 64, 2, 2, 2, 0><<<dim3(DD / 64, MM / 64), 256, 0, stream>>>(
        x_bf, w_in, in_b, nullptr, h, nullptr, MM, DD, DIN);
    gemm_t<64, 64, 2, 2, 2, 0><<<dim3(DD / 64, MM / 64), 256, 0, stream>>>(
        Zb, w_cpe, cpe_b, nullptr, cpe_pre, nullptr, MM, DD, FEATP);
    embed_ep_kernel<<<MM, 256, 0, stream>>>(cpe_pre, e, lengths, cpe_ln_g, cpe_ln_b, gain, h);

    for (int i = 0; i < NLAYER; ++i) {
        ln_bf16_kernel<<<MM, 256, 0, stream>>>(h, act1, ln1_g + (size_t)i * DD, ln1_b + (size_t)i * DD);
        gemm_t<64, 128, 2, 4, 2, 1><<<dim3(1536 / 128, MM / 64), 256, 0, stream>>>(
            act1, w_inproj + (size_t)i * 1536 * 512, inproj_b + (size_t)i * 1536,
            nullptr, nullptr, qkvb, MM, 1536, DD);
        vtrans_kernel<<<dim3(LL / 64, HH, BB), 256, 0, stream>>>(qkvb, vtb);
        attn_mfma<<<512, 256, 0, stream>>>(qkvb, vtb, c_local, srow, lengths, alpha, act1);
        gemm_t<64, 64, 2, 2, 2, 2><<<dim3(DD / 64, MM / 64), 256, 0, stream>>>(
            act1, w_outproj + (size_t)i * 512 * 512, outproj_b + (size_t)i * DD,
            h, h, nullptr, MM, DD, DD);
        ln_bf16_kernel<<<MM, 256, 0, stream>>>(h, act1, ln2_g + (size_t)i * DD, ln2_b + (size_t)i * DD);
        gemm_t<128, 128, 4, 4, 2, 3><<<dim3(DFF / 128, MM / 128), 256, 0, stream>>>(
            act1, w_ff1 + (size_t)i * 2048 * 512, ff_b1 + (size_t)i * DFF,
            nullptr, nullptr, ffb, MM, DFF, DD);
        gemm_t<64, 64, 2, 2, 2, 2><<<dim3(DD / 64, MM / 64), 256, 0, stream>>>(
            ffb, w_ff2 + (size_t)i * 512 * 2048, ff_b2 + (size_t)i * DD,
            h, h, nullptr, MM, DD, DFF);
    }
    ln_kernel<<<MM, 256, 0, stream>>>(h, (float*)d_out, out_ln_g, out_ln_b);
}